// Round 3
// baseline (1789.126 us; speedup 1.0000x reference)
//
#include <hip/hip_runtime.h>
#include <math.h>

// DCRNN (1 step, H0=0) + GCN + BN + Linear. N=50000, F=32, H=64, K=3, E=800000.
//
// Algebra: H0==0 => R gate unused; hidden half of XH stays zero through hops,
// so only W[:,:,:32,:] matters. F = [x, To1, Ti1, To2, Ti2] (N x 160),
//   Z = sigmoid(F@WcZ + bz), H = (1-Z)*tanh(F@WcH + bh), xw = H@gcn_w.
// R3: (a) GEMMs: 4-node register blocking + transposed LDS weights (stride 164)
//     read via ds_read_b128 — kills the LDS b32 issue bottleneck (R2: 230us,
//     VALUBusy 17%). (b) CSR build (hist+scan+fill) turns all scatter-atomics
//     (2 hops + gcn edge, ~154M f32 atomics) into coalesced gathers.

#define BN_EPS 1e-5f
#define WT_STRIDE 164   // 160 + 4: 16B-aligned rows, even bank spread for b128

// ---- histogram: weighted degrees (float) + edge counts (int) ----------------
__global__ void k_deg2(const int* __restrict__ row, const int* __restrict__ col,
                       const float* __restrict__ ew,
                       float* __restrict__ deg_out, float* __restrict__ deg_in,
                       int* __restrict__ cnt_col, int* __restrict__ cnt_row, int E) {
    int e = blockIdx.x * blockDim.x + threadIdx.x;
    if (e >= E) return;
    int r = row[e], c = col[e];
    float w = ew[e];
    atomicAdd(&deg_out[r], w);
    atomicAdd(&deg_in[c], w);
    atomicAdd(&cnt_col[c], 1);
    atomicAdd(&cnt_row[r], 1);
}

// ---- 3-pass exclusive scan of cnt_col / cnt_row into off_col / off_row ------
__device__ int block_scan_excl(int v, int tid, int* buf) {
    buf[tid] = v; __syncthreads();
    for (int d = 1; d < 256; d <<= 1) {
        int t = buf[tid];
        int add = (tid >= d) ? buf[tid - d] : 0;
        __syncthreads();
        buf[tid] = t + add;
        __syncthreads();
    }
    return buf[tid] - v;   // exclusive prefix
}

// pass 1: per-256-chunk totals. grid = 2*NB blocks; array a = blk/NB.
__global__ void k_scan1(const int* __restrict__ cnt_col, const int* __restrict__ cnt_row,
                        int* __restrict__ bsum, int NB, int N) {
    __shared__ int buf[256];
    int a = blockIdx.x / NB, blk = blockIdx.x % NB;
    const int* cnt = a == 0 ? cnt_col : cnt_row;
    int i = blk * 256 + threadIdx.x;
    int v = (i < N) ? cnt[i] : 0;
    int ex = block_scan_excl(v, threadIdx.x, buf);
    if (threadIdx.x == 255) bsum[a * 256 + blk] = ex + v;
}

// pass 2: scan the block totals (NB<=256). grid = 2 blocks.
__global__ void k_scan2(int* __restrict__ bsum) {
    __shared__ int buf[256];
    int a = blockIdx.x;
    int v = bsum[a * 256 + threadIdx.x];   // zero-initialized beyond NB
    int ex = block_scan_excl(v, threadIdx.x, buf);
    bsum[a * 256 + threadIdx.x] = ex;
}

// pass 3: final offsets. grid = 2*NB blocks.
__global__ void k_scan3(const int* __restrict__ cnt_col, const int* __restrict__ cnt_row,
                        const int* __restrict__ bsum,
                        int* __restrict__ off_col, int* __restrict__ off_row,
                        int NB, int N) {
    __shared__ int buf[256];
    int a = blockIdx.x / NB, blk = blockIdx.x % NB;
    const int* cnt = a == 0 ? cnt_col : cnt_row;
    int* off = a == 0 ? off_col : off_row;
    int i = blk * 256 + threadIdx.x;
    int v = (i < N) ? cnt[i] : 0;
    int ex = block_scan_excl(v, threadIdx.x, buf);
    if (i < N) off[i] = bsum[a * 256 + blk] + ex;
}

// dis[i] = rsqrt(#in-edges + 1)  (+1 = self loop)
__global__ void k_dis(const int* __restrict__ cnt_col, float* __restrict__ dis, int N) {
    int i = blockIdx.x * blockDim.x + threadIdx.x;
    if (i >= N) return;
    dis[i] = rsqrtf((float)cnt_col[i] + 1.0f);
}

// fill both CSRs: ent_col[off_col[c]+slot] = (row, w_out); ent_row: (col, w_in)
__global__ void k_fill(const int* __restrict__ row, const int* __restrict__ col,
                       const float* __restrict__ ew,
                       const float* __restrict__ deg_out, const float* __restrict__ deg_in,
                       const int* __restrict__ off_col, const int* __restrict__ off_row,
                       int* __restrict__ cur_col, int* __restrict__ cur_row,
                       int2* __restrict__ ent_col, int2* __restrict__ ent_row, int E) {
    int e = blockIdx.x * blockDim.x + threadIdx.x;
    if (e >= E) return;
    int r = row[e], c = col[e];
    float w = ew[e];
    float dO = deg_out[r], dI = deg_in[c];
    float wout = dO > 0.f ? w / dO : 0.f;
    float win  = dI > 0.f ? w / dI : 0.f;
    int sc = atomicAdd(&cur_col[c], 1);
    ent_col[off_col[c] + sc] = make_int2(r, __float_as_int(wout));
    int sr = atomicAdd(&cur_row[r], 1);
    ent_row[off_row[r] + sr] = make_int2(c, __float_as_int(win));
}

// one diffusion hop, both directions, gather form. half-wave (32 lanes) = one
// (dest,dir); lane = feature. out-dir: Do[d] = sum w_out*So[src] over in-edges
// of d (CSR-by-col); in-dir: Di[d] = sum w_in*Si[dst] over out-edges (CSR-by-row).
__global__ void k_hop_gather(const int2* __restrict__ ent_col, const int2* __restrict__ ent_row,
                             const int* __restrict__ off_col, const int* __restrict__ off_row,
                             const int* __restrict__ cnt_col, const int* __restrict__ cnt_row,
                             const float* __restrict__ So, const float* __restrict__ Si,
                             float* __restrict__ Do, float* __restrict__ Di, int N) {
    int t = blockIdx.x * blockDim.x + threadIdx.x;
    int f = t & 31;
    int p = t >> 5;
    if (p >= 2 * N) return;
    const int2* ent; const float* S; float* D;
    int d, base, cnt;
    if (p < N) {
        d = p; ent = ent_col; S = So; D = Do;
        base = off_col[d]; cnt = cnt_col[d];
    } else {
        d = p - N; ent = ent_row; S = Si; D = Di;
        base = off_row[d]; cnt = cnt_row[d];
    }
    float acc = 0.f;
    for (int j = 0; j < cnt; ++j) {
        int2 e8 = ent[base + j];
        acc += __int_as_float(e8.y) * S[e8.x * 32 + f];
    }
    D[d * 32 + f] = acc;
}

// ---- GEMM helpers -----------------------------------------------------------
// transposed combined dconv weight into LDS: wT[c][k], c=out channel, k=0..159
__device__ inline void fill_wT(float* wT, const float* __restrict__ W, int tid, int bdim) {
    for (int t = tid; t < 160 * 64; t += bdim) {
        int k = t >> 6, c = t & 63;
        int blk = k >> 5, r = k & 31;
        float v;
        if (blk == 0) {
            v = W[r * 64 + c] + W[(288 + r) * 64 + c];            // W[0,0]+W[1,0]
        } else {
            int kk = (blk + 1) >> 1;                               // 1,1,2,2
            int dd = (blk + 1) & 1;                                // 0,1,0,1
            v = W[((dd * 3 + kk) * 96 + r) * 64 + c];
        }
        wT[c * WT_STRIDE + k] = v;
    }
}

// one 32-wide feature block for 4 nodes against this lane's weight row.
// wrow points at wT[lane] + 32*b.  p0..p3 = node row pointers (float4).
#define GEMM_BLK(WROW, P0, P1, P2, P3, A0, A1, A2, A3)                          \
    _Pragma("unroll")                                                           \
    for (int k4 = 0; k4 < 8; ++k4) {                                            \
        float4 w4 = *(const float4*)((WROW) + k4 * 4);                          \
        float4 f0 = (P0)[k4], f1 = (P1)[k4], f2 = (P2)[k4], f3 = (P3)[k4];      \
        A0 += f0.x * w4.x + f0.y * w4.y + f0.z * w4.z + f0.w * w4.w;            \
        A1 += f1.x * w4.x + f1.y * w4.y + f1.z * w4.z + f1.w * w4.w;            \
        A2 += f2.x * w4.x + f2.y * w4.y + f2.z * w4.z + f2.w * w4.w;            \
        A3 += f3.x * w4.x + f3.y * w4.y + f3.z * w4.z + f3.w * w4.w;            \
    }

// Z = sigmoid(F @ WcZ + bz). wave = 4 nodes, lane = out channel.
__global__ __launch_bounds__(256) void k_z(
    const float* __restrict__ x, const float* __restrict__ txo1,
    const float* __restrict__ txi1, const float* __restrict__ txo2,
    const float* __restrict__ txi2,
    const float* __restrict__ Wz, const float* __restrict__ bz,
    float* __restrict__ Z, int N) {
    __shared__ float wl[64 * WT_STRIDE];           // ~41 KB
    fill_wT(wl, Wz, threadIdx.x, blockDim.x);
    __syncthreads();
    int lane = threadIdx.x & 63;
    int wave = (blockIdx.x * blockDim.x + threadIdx.x) >> 6;
    int nw = (gridDim.x * blockDim.x) >> 6;
    const float* wrow = wl + lane * WT_STRIDE;
    float bl = bz[lane];
    for (int i0 = wave * 4; i0 < N; i0 += nw * 4) {
        int i1 = min(i0 + 1, N - 1), i2 = min(i0 + 2, N - 1), i3 = min(i0 + 3, N - 1);
        float a0 = 0.f, a1 = 0.f, a2 = 0.f, a3 = 0.f;
        {
            const float4* p0 = (const float4*)(x + i0 * 32);
            const float4* p1 = (const float4*)(x + i1 * 32);
            const float4* p2 = (const float4*)(x + i2 * 32);
            const float4* p3 = (const float4*)(x + i3 * 32);
            GEMM_BLK(wrow, p0, p1, p2, p3, a0, a1, a2, a3)
        }
        {
            const float4* p0 = (const float4*)(txo1 + i0 * 32);
            const float4* p1 = (const float4*)(txo1 + i1 * 32);
            const float4* p2 = (const float4*)(txo1 + i2 * 32);
            const float4* p3 = (const float4*)(txo1 + i3 * 32);
            GEMM_BLK(wrow + 32, p0, p1, p2, p3, a0, a1, a2, a3)
        }
        {
            const float4* p0 = (const float4*)(txi1 + i0 * 32);
            const float4* p1 = (const float4*)(txi1 + i1 * 32);
            const float4* p2 = (const float4*)(txi1 + i2 * 32);
            const float4* p3 = (const float4*)(txi1 + i3 * 32);
            GEMM_BLK(wrow + 64, p0, p1, p2, p3, a0, a1, a2, a3)
        }
        {
            const float4* p0 = (const float4*)(txo2 + i0 * 32);
            const float4* p1 = (const float4*)(txo2 + i1 * 32);
            const float4* p2 = (const float4*)(txo2 + i2 * 32);
            const float4* p3 = (const float4*)(txo2 + i3 * 32);
            GEMM_BLK(wrow + 96, p0, p1, p2, p3, a0, a1, a2, a3)
        }
        {
            const float4* p0 = (const float4*)(txi2 + i0 * 32);
            const float4* p1 = (const float4*)(txi2 + i1 * 32);
            const float4* p2 = (const float4*)(txi2 + i2 * 32);
            const float4* p3 = (const float4*)(txi2 + i3 * 32);
            GEMM_BLK(wrow + 128, p0, p1, p2, p3, a0, a1, a2, a3)
        }
        Z[i0 * 64 + lane] = 1.0f / (1.0f + expf(-(a0 + bl)));
        if (i0 + 1 < N) Z[i1 * 64 + lane] = 1.0f / (1.0f + expf(-(a1 + bl)));
        if (i0 + 2 < N) Z[i2 * 64 + lane] = 1.0f / (1.0f + expf(-(a2 + bl)));
        if (i0 + 3 < N) Z[i3 * 64 + lane] = 1.0f / (1.0f + expf(-(a3 + bl)));
    }
}

// H = (1-Z)*tanh(F @ WcH + bh) in regs, then xw = H @ gcn_w via shfl.
__global__ __launch_bounds__(256) void k_hxw(
    const float* __restrict__ x, const float* __restrict__ txo1,
    const float* __restrict__ txi1, const float* __restrict__ txo2,
    const float* __restrict__ txi2,
    const float* __restrict__ Wh, const float* __restrict__ bhv,
    const float* __restrict__ gcn_w, const float* __restrict__ Z,
    float* __restrict__ xw, int N) {
    __shared__ float wl[64 * WT_STRIDE];           // ~41 KB
    __shared__ float gw[64 * 64];                  // 16 KB
    fill_wT(wl, Wh, threadIdx.x, blockDim.x);
    for (int idx = threadIdx.x; idx < 64 * 64; idx += blockDim.x) gw[idx] = gcn_w[idx];
    __syncthreads();
    int lane = threadIdx.x & 63;
    int wave = (blockIdx.x * blockDim.x + threadIdx.x) >> 6;
    int nw = (gridDim.x * blockDim.x) >> 6;
    const float* wrow = wl + lane * WT_STRIDE;
    float bl = bhv[lane];
    for (int i0 = wave * 4; i0 < N; i0 += nw * 4) {
        int i1 = min(i0 + 1, N - 1), i2 = min(i0 + 2, N - 1), i3 = min(i0 + 3, N - 1);
        float a0 = 0.f, a1 = 0.f, a2 = 0.f, a3 = 0.f;
        {
            const float4* p0 = (const float4*)(x + i0 * 32);
            const float4* p1 = (const float4*)(x + i1 * 32);
            const float4* p2 = (const float4*)(x + i2 * 32);
            const float4* p3 = (const float4*)(x + i3 * 32);
            GEMM_BLK(wrow, p0, p1, p2, p3, a0, a1, a2, a3)
        }
        {
            const float4* p0 = (const float4*)(txo1 + i0 * 32);
            const float4* p1 = (const float4*)(txo1 + i1 * 32);
            const float4* p2 = (const float4*)(txo1 + i2 * 32);
            const float4* p3 = (const float4*)(txo1 + i3 * 32);
            GEMM_BLK(wrow + 32, p0, p1, p2, p3, a0, a1, a2, a3)
        }
        {
            const float4* p0 = (const float4*)(txi1 + i0 * 32);
            const float4* p1 = (const float4*)(txi1 + i1 * 32);
            const float4* p2 = (const float4*)(txi1 + i2 * 32);
            const float4* p3 = (const float4*)(txi1 + i3 * 32);
            GEMM_BLK(wrow + 64, p0, p1, p2, p3, a0, a1, a2, a3)
        }
        {
            const float4* p0 = (const float4*)(txo2 + i0 * 32);
            const float4* p1 = (const float4*)(txo2 + i1 * 32);
            const float4* p2 = (const float4*)(txo2 + i2 * 32);
            const float4* p3 = (const float4*)(txo2 + i3 * 32);
            GEMM_BLK(wrow + 96, p0, p1, p2, p3, a0, a1, a2, a3)
        }
        {
            const float4* p0 = (const float4*)(txi2 + i0 * 32);
            const float4* p1 = (const float4*)(txi2 + i1 * 32);
            const float4* p2 = (const float4*)(txi2 + i2 * 32);
            const float4* p3 = (const float4*)(txi2 + i3 * 32);
            GEMM_BLK(wrow + 128, p0, p1, p2, p3, a0, a1, a2, a3)
        }
        float h0 = (1.0f - Z[i0 * 64 + lane]) * tanhf(a0 + bl);
        float h1 = (1.0f - Z[i1 * 64 + lane]) * tanhf(a1 + bl);
        float h2 = (1.0f - Z[i2 * 64 + lane]) * tanhf(a2 + bl);
        float h3 = (1.0f - Z[i3 * 64 + lane]) * tanhf(a3 + bl);
        float x0 = 0.f, x1 = 0.f, x2 = 0.f, x3 = 0.f;
        for (int r = 0; r < 64; ++r) {
            float g = gw[r * 64 + lane];
            x0 += __shfl(h0, r, 64) * g;
            x1 += __shfl(h1, r, 64) * g;
            x2 += __shfl(h2, r, 64) * g;
            x3 += __shfl(h3, r, 64) * g;
        }
        xw[i0 * 64 + lane] = x0;
        if (i0 + 1 < N) xw[i1 * 64 + lane] = x1;
        if (i0 + 2 < N) xw[i2 * 64 + lane] = x2;
        if (i0 + 3 < N) xw[i3 * 64 + lane] = x3;
    }
}

// GCN gather + bias + ReLU + BN stats, fused. wave = dest node, lane = channel.
__global__ void k_gcn_fused(const int2* __restrict__ ent_col,
                            const int* __restrict__ off_col, const int* __restrict__ cnt_col,
                            const float* __restrict__ dis, const float* __restrict__ xw,
                            const float* __restrict__ gcn_b,
                            float* __restrict__ y, float* __restrict__ stats, int N) {
    int lane = threadIdx.x & 63;
    int wave = (blockIdx.x * blockDim.x + threadIdx.x) >> 6;
    int nw = (gridDim.x * blockDim.x) >> 6;
    float bl = gcn_b[lane];
    float s = 0.f, s2 = 0.f;
    for (int d = wave; d < N; d += nw) {
        float dd = dis[d];
        float acc = dd * dd * xw[d * 64 + lane];
        int base = off_col[d], cnt = cnt_col[d];
        for (int j = 0; j < cnt; ++j) {
            int2 e8 = ent_col[base + j];
            acc += dis[e8.x] * dd * xw[e8.x * 64 + lane];
        }
        float v = acc + bl;
        v = v > 0.f ? v : 0.f;
        y[d * 64 + lane] = v;
        s += v; s2 += v * v;
    }
    atomicAdd(&stats[lane], s);
    atomicAdd(&stats[64 + lane], s2);
}

// out[i] = sum_f ((y[i,f]-mean)*istd*gamma + beta) * lw[f] + lb   (wave per node)
__global__ void k_final(const float* __restrict__ y, const float* __restrict__ stats,
                        const float* __restrict__ gma, const float* __restrict__ bta,
                        const float* __restrict__ lw, const float* __restrict__ lb,
                        float* __restrict__ out, int N) {
    int lane = threadIdx.x & 63;
    int wave = (blockIdx.x * blockDim.x + threadIdx.x) >> 6;
    if (wave >= N) return;
    float invN = 1.0f / (float)N;
    float mean = stats[lane] * invN;
    float var  = stats[64 + lane] * invN - mean * mean;   // biased var
    float istd = rsqrtf(var + BN_EPS);
    float v = y[wave * 64 + lane];
    float t = (v - mean) * istd * gma[lane] + bta[lane];
    float p = t * lw[lane];
    for (int off = 32; off > 0; off >>= 1)
        p += __shfl_down(p, off, 64);
    if (lane == 0) out[wave] = p + lb[0];
}

extern "C" void kernel_launch(void* const* d_in, const int* in_sizes, int n_in,
                              void* d_out, int out_size, void* d_ws, size_t ws_size,
                              hipStream_t stream) {
    const float* x     = (const float*)d_in[0];
    const int*   ei    = (const int*)d_in[1];
    const float* ew    = (const float*)d_in[2];
    const float* Wz    = (const float*)d_in[3];
    const float* bz    = (const float*)d_in[4];
    // d_in[5] = Wr, d_in[6] = br : provably unused (H0 == 0)
    const float* Wh    = (const float*)d_in[7];
    const float* bhv   = (const float*)d_in[8];
    const float* gcn_w = (const float*)d_in[9];
    const float* gcn_b = (const float*)d_in[10];
    const float* gma   = (const float*)d_in[11];
    const float* bta   = (const float*)d_in[12];
    const float* lw    = (const float*)d_in[13];
    const float* lb    = (const float*)d_in[14];
    float* out = (float*)d_out;

    const int N = in_sizes[0] / 32;
    const int E = in_sizes[2];
    const int* row = ei;
    const int* col = ei + E;
    const int NB = (N + 255) / 256;       // 196 <= 256

    // workspace layout (4-byte words)
    float* ws      = (float*)d_ws;
    float* deg_out = ws;                              // N f
    float* deg_in  = ws + N;                          // N f
    int*   cnt_col = (int*)(ws + 2 * (size_t)N);      // N i
    int*   cnt_row = (int*)(ws + 3 * (size_t)N);      // N i
    int*   cur_col = (int*)(ws + 4 * (size_t)N);      // N i
    int*   cur_row = (int*)(ws + 5 * (size_t)N);      // N i
    float* stats   = ws + 6 * (size_t)N;              // 128 f
    int*   bsum    = (int*)(ws + 6 * (size_t)N + 128);// 512 i  <- end of zero region
    size_t Z0      = 6 * (size_t)N + 640;
    int*   off_col = (int*)(ws + Z0);                 // N i
    int*   off_row = (int*)(ws + Z0 + N);             // N i
    float* dis     = ws + Z0 + 2 * (size_t)N;         // N f
    float* txo1    = ws + Z0 + 3 * (size_t)N;         // 32N
    float* txi1    = txo1 + 32 * (size_t)N;           // 32N
    float* txo2    = txi1 + 32 * (size_t)N;           // 32N
    float* txi2    = txo2 + 32 * (size_t)N;           // 32N
    int2*  ent_col = (int2*)(txi2 + 32 * (size_t)N);  // E int2 (2E words)
    int2*  ent_row = (int2*)((float*)ent_col + 2 * (size_t)E); // E int2
    float* Zbuf    = (float*)ent_row;                 // 64N, overlays ent_row (dead after hops)
    float* xw      = Zbuf + 64 * (size_t)N;           // 64N
    float* ybuf    = txo1;                            // 64N, overlays txo1+txi1 (dead after k_hxw)

    size_t zero_bytes = (6 * (size_t)N + 640) * sizeof(float);
    hipMemsetAsync(d_ws, 0, zero_bytes, stream);

    int be = (E + 255) / 256;
    k_deg2 <<<be, 256, 0, stream>>>(row, col, ew, deg_out, deg_in, cnt_col, cnt_row, E);
    k_scan1<<<2 * NB, 256, 0, stream>>>(cnt_col, cnt_row, bsum, NB, N);
    k_scan2<<<2, 256, 0, stream>>>(bsum);
    k_scan3<<<2 * NB, 256, 0, stream>>>(cnt_col, cnt_row, bsum, off_col, off_row, NB, N);
    k_dis  <<<NB, 256, 0, stream>>>(cnt_col, dis, N);
    k_fill <<<be, 256, 0, stream>>>(row, col, ew, deg_out, deg_in,
                                    off_col, off_row, cur_col, cur_row,
                                    ent_col, ent_row, E);

    int bhop = (2 * N * 32 + 255) / 256;
    k_hop_gather<<<bhop, 256, 0, stream>>>(ent_col, ent_row, off_col, off_row,
                                           cnt_col, cnt_row, x, x, txo1, txi1, N);
    k_hop_gather<<<bhop, 256, 0, stream>>>(ent_col, ent_row, off_col, off_row,
                                           cnt_col, cnt_row, txo1, txi1, txo2, txi2, N);

    k_z  <<<768, 256, 0, stream>>>(x, txo1, txi1, txo2, txi2, Wz, bz, Zbuf, N);
    k_hxw<<<512, 256, 0, stream>>>(x, txo1, txi1, txo2, txi2, Wh, bhv, gcn_w, Zbuf, xw, N);

    k_gcn_fused<<<512, 256, 0, stream>>>(ent_col, off_col, cnt_col, dis, xw,
                                         gcn_b, ybuf, stats, N);
    k_final<<<(N + 3) / 4, 256, 0, stream>>>(ybuf, stats, gma, bta, lw, lb, out, N);
}

// Round 4
// 1033.581 us; speedup vs baseline: 1.7310x; 1.7310x over previous
//
#include <hip/hip_runtime.h>
#include <math.h>

// DCRNN (1 step, H0=0) + GCN + BN + Linear. N=50000, F=32, H=64, K=3, E=800000.
//
// Algebra: H0==0 => R gate unused; hidden half of XH stays zero through hops,
// so only W[:,:,:32,:] matters. F = [x, To1, Ti1, To2, Ti2] (N x 160),
//   Z = sigmoid(F@WcZ + bz), H = (1-Z)*tanh(F@WcH + bh), xw = H@gcn_w.
// R4: CSR gathers kept from R3 (atomic scatters were ~700us in R2).
//     GEMMs reverted to R2 bodies (R3's 4-node blocking spilled: VGPR 256,
//     426MB scratch writes; R2 body is 160 VGPR, 0 conflicts, no spill).

#define BN_EPS 1e-5f

// ---- histogram: weighted degrees (float) + edge counts (int) ----------------
__global__ void k_deg2(const int* __restrict__ row, const int* __restrict__ col,
                       const float* __restrict__ ew,
                       float* __restrict__ deg_out, float* __restrict__ deg_in,
                       int* __restrict__ cnt_col, int* __restrict__ cnt_row, int E) {
    int e = blockIdx.x * blockDim.x + threadIdx.x;
    if (e >= E) return;
    int r = row[e], c = col[e];
    float w = ew[e];
    atomicAdd(&deg_out[r], w);
    atomicAdd(&deg_in[c], w);
    atomicAdd(&cnt_col[c], 1);
    atomicAdd(&cnt_row[r], 1);
}

// ---- 3-pass exclusive scan of cnt_col / cnt_row into off_col / off_row ------
__device__ int block_scan_excl(int v, int tid, int* buf) {
    buf[tid] = v; __syncthreads();
    for (int d = 1; d < 256; d <<= 1) {
        int t = buf[tid];
        int add = (tid >= d) ? buf[tid - d] : 0;
        __syncthreads();
        buf[tid] = t + add;
        __syncthreads();
    }
    return buf[tid] - v;   // exclusive prefix
}

// pass 1: per-256-chunk totals. grid = 2*NB blocks; array a = blk/NB.
__global__ void k_scan1(const int* __restrict__ cnt_col, const int* __restrict__ cnt_row,
                        int* __restrict__ bsum, int NB, int N) {
    __shared__ int buf[256];
    int a = blockIdx.x / NB, blk = blockIdx.x % NB;
    const int* cnt = a == 0 ? cnt_col : cnt_row;
    int i = blk * 256 + threadIdx.x;
    int v = (i < N) ? cnt[i] : 0;
    int ex = block_scan_excl(v, threadIdx.x, buf);
    if (threadIdx.x == 255) bsum[a * 256 + blk] = ex + v;
}

// pass 2: scan the block totals (NB<=256). grid = 2 blocks.
__global__ void k_scan2(int* __restrict__ bsum) {
    __shared__ int buf[256];
    int a = blockIdx.x;
    int v = bsum[a * 256 + threadIdx.x];   // zero-initialized beyond NB
    int ex = block_scan_excl(v, threadIdx.x, buf);
    bsum[a * 256 + threadIdx.x] = ex;
}

// pass 3: final offsets. grid = 2*NB blocks.
__global__ void k_scan3(const int* __restrict__ cnt_col, const int* __restrict__ cnt_row,
                        const int* __restrict__ bsum,
                        int* __restrict__ off_col, int* __restrict__ off_row,
                        int NB, int N) {
    __shared__ int buf[256];
    int a = blockIdx.x / NB, blk = blockIdx.x % NB;
    const int* cnt = a == 0 ? cnt_col : cnt_row;
    int* off = a == 0 ? off_col : off_row;
    int i = blk * 256 + threadIdx.x;
    int v = (i < N) ? cnt[i] : 0;
    int ex = block_scan_excl(v, threadIdx.x, buf);
    if (i < N) off[i] = bsum[a * 256 + blk] + ex;
}

// dis[i] = rsqrt(#in-edges + 1)  (+1 = self loop)
__global__ void k_dis(const int* __restrict__ cnt_col, float* __restrict__ dis, int N) {
    int i = blockIdx.x * blockDim.x + threadIdx.x;
    if (i >= N) return;
    dis[i] = rsqrtf((float)cnt_col[i] + 1.0f);
}

// fill both CSRs: ent_col[off_col[c]+slot] = (row, w_out); ent_row: (col, w_in)
__global__ void k_fill(const int* __restrict__ row, const int* __restrict__ col,
                       const float* __restrict__ ew,
                       const float* __restrict__ deg_out, const float* __restrict__ deg_in,
                       const int* __restrict__ off_col, const int* __restrict__ off_row,
                       int* __restrict__ cur_col, int* __restrict__ cur_row,
                       int2* __restrict__ ent_col, int2* __restrict__ ent_row, int E) {
    int e = blockIdx.x * blockDim.x + threadIdx.x;
    if (e >= E) return;
    int r = row[e], c = col[e];
    float w = ew[e];
    float dO = deg_out[r], dI = deg_in[c];
    float wout = dO > 0.f ? w / dO : 0.f;
    float win  = dI > 0.f ? w / dI : 0.f;
    int sc = atomicAdd(&cur_col[c], 1);
    ent_col[off_col[c] + sc] = make_int2(r, __float_as_int(wout));
    int sr = atomicAdd(&cur_row[r], 1);
    ent_row[off_row[r] + sr] = make_int2(c, __float_as_int(win));
}

// one diffusion hop, both directions, gather form. half-wave (32 lanes) = one
// (dest,dir); lane = feature. out-dir: Do[d] = sum w_out*So[src] over in-edges
// of d (CSR-by-col); in-dir: Di[d] = sum w_in*Si[dst] over out-edges (CSR-by-row).
__global__ void k_hop_gather(const int2* __restrict__ ent_col, const int2* __restrict__ ent_row,
                             const int* __restrict__ off_col, const int* __restrict__ off_row,
                             const int* __restrict__ cnt_col, const int* __restrict__ cnt_row,
                             const float* __restrict__ So, const float* __restrict__ Si,
                             float* __restrict__ Do, float* __restrict__ Di, int N) {
    int t = blockIdx.x * blockDim.x + threadIdx.x;
    int f = t & 31;
    int p = t >> 5;
    if (p >= 2 * N) return;
    const int2* ent; const float* S; float* D;
    int d, base, cnt;
    if (p < N) {
        d = p; ent = ent_col; S = So; D = Do;
        base = off_col[d]; cnt = cnt_col[d];
    } else {
        d = p - N; ent = ent_row; S = Si; D = Di;
        base = off_row[d]; cnt = cnt_row[d];
    }
    float acc = 0.f;
    for (int j = 0; j < cnt; ++j) {
        int2 e8 = ent[base + j];
        acc += __int_as_float(e8.y) * S[e8.x * 32 + f];
    }
    D[d * 32 + f] = acc;
}

// ---- GEMM helpers (R2 bodies: row-major weight LDS, broadcast-friendly) -----
// fills lds[160*64] with the combined dconv weight built from W (2,3,96,64), rows [:32]
__device__ inline void fill_comb_w(float* lds, const float* __restrict__ W, int tid, int bdim) {
    for (int idx = tid; idx < 160 * 64; idx += bdim) {
        int rr = idx >> 6, c = idx & 63;
        int blk = rr >> 5, r = rr & 31;
        float v;
        if (blk == 0) {
            v = W[r * 64 + c] + W[(288 + r) * 64 + c];            // W[0,0]+W[1,0]
        } else {
            int k = (blk + 1) >> 1;                                // 1,1,2,2
            int d = (blk + 1) & 1;                                 // 0,1,0,1
            v = W[((d * 3 + k) * 96 + r) * 64 + c];
        }
        lds[idx] = v;
    }
}

// dot of one 32-float feature row with weight rows [r0..r0+32) column `lane`.
__device__ inline float dot32(const float* __restrict__ rowp, const float* wl, int lane) {
    const float4* r4p = reinterpret_cast<const float4*>(rowp);
    float acc = 0.f;
#pragma unroll
    for (int r4 = 0; r4 < 8; ++r4) {
        float4 f = r4p[r4];
        const float* w = wl + r4 * 256 + lane;
        acc += f.x * w[0] + f.y * w[64] + f.z * w[128] + f.w * w[192];
    }
    return acc;
}

// Z = sigmoid(F @ WcZ + bz).  wave = 1 node, lane = output channel.
__global__ __launch_bounds__(256) void k_z(
    const float* __restrict__ x, const float* __restrict__ txo1,
    const float* __restrict__ txi1, const float* __restrict__ txo2,
    const float* __restrict__ txi2,
    const float* __restrict__ Wz, const float* __restrict__ bz,
    float* __restrict__ Z, int N) {
    __shared__ float wl[160 * 64];                 // 40 KB
    fill_comb_w(wl, Wz, threadIdx.x, blockDim.x);
    __syncthreads();
    int lane = threadIdx.x & 63;
    int wave = (blockIdx.x * blockDim.x + threadIdx.x) >> 6;
    int nw = (gridDim.x * blockDim.x) >> 6;
    float bl = bz[lane];
    for (int i = wave; i < N; i += nw) {
        float acc = dot32(x    + i * 32, wl,             lane)
                  + dot32(txo1 + i * 32, wl +  32 * 64,  lane)
                  + dot32(txi1 + i * 32, wl +  64 * 64,  lane)
                  + dot32(txo2 + i * 32, wl +  96 * 64,  lane)
                  + dot32(txi2 + i * 32, wl + 128 * 64,  lane);
        float v = acc + bl;
        Z[i * 64 + lane] = 1.0f / (1.0f + expf(-v));
    }
}

// H = (1-Z)*tanh(F @ WcH + bh)  (in registers), then xw = H @ gcn_w via shfl.
__global__ __launch_bounds__(256) void k_hxw(
    const float* __restrict__ x, const float* __restrict__ txo1,
    const float* __restrict__ txi1, const float* __restrict__ txo2,
    const float* __restrict__ txi2,
    const float* __restrict__ Wh, const float* __restrict__ bhv,
    const float* __restrict__ gcn_w, const float* __restrict__ Z,
    float* __restrict__ xw, int N) {
    __shared__ float wl[160 * 64];                 // 40 KB
    __shared__ float gw[64 * 64];                  // 16 KB  (total 56 KB)
    fill_comb_w(wl, Wh, threadIdx.x, blockDim.x);
    for (int idx = threadIdx.x; idx < 64 * 64; idx += blockDim.x) gw[idx] = gcn_w[idx];
    __syncthreads();
    int lane = threadIdx.x & 63;
    int wave = (blockIdx.x * blockDim.x + threadIdx.x) >> 6;
    int nw = (gridDim.x * blockDim.x) >> 6;
    float bl = bhv[lane];
    for (int i = wave; i < N; i += nw) {
        float acc = dot32(x    + i * 32, wl,             lane)
                  + dot32(txo1 + i * 32, wl +  32 * 64,  lane)
                  + dot32(txi1 + i * 32, wl +  64 * 64,  lane)
                  + dot32(txo2 + i * 32, wl +  96 * 64,  lane)
                  + dot32(txi2 + i * 32, wl + 128 * 64,  lane);
        float zv = Z[i * 64 + lane];
        float hv = (1.0f - zv) * tanhf(acc + bl);
        float ax = 0.f;
#pragma unroll
        for (int r = 0; r < 64; ++r) {
            ax += __shfl(hv, r, 64) * gw[r * 64 + lane];
        }
        xw[i * 64 + lane] = ax;
    }
}

// GCN gather + bias + ReLU + BN stats, fused. wave = dest node, lane = channel.
__global__ void k_gcn_fused(const int2* __restrict__ ent_col,
                            const int* __restrict__ off_col, const int* __restrict__ cnt_col,
                            const float* __restrict__ dis, const float* __restrict__ xw,
                            const float* __restrict__ gcn_b,
                            float* __restrict__ y, float* __restrict__ stats, int N) {
    int lane = threadIdx.x & 63;
    int wave = (blockIdx.x * blockDim.x + threadIdx.x) >> 6;
    int nw = (gridDim.x * blockDim.x) >> 6;
    float bl = gcn_b[lane];
    float s = 0.f, s2 = 0.f;
    for (int d = wave; d < N; d += nw) {
        float dd = dis[d];
        float acc = dd * dd * xw[d * 64 + lane];
        int base = off_col[d], cnt = cnt_col[d];
        for (int j = 0; j < cnt; ++j) {
            int2 e8 = ent_col[base + j];
            acc += dis[e8.x] * dd * xw[e8.x * 64 + lane];
        }
        float v = acc + bl;
        v = v > 0.f ? v : 0.f;
        y[d * 64 + lane] = v;
        s += v; s2 += v * v;
    }
    atomicAdd(&stats[lane], s);
    atomicAdd(&stats[64 + lane], s2);
}

// out[i] = sum_f ((y[i,f]-mean)*istd*gamma + beta) * lw[f] + lb   (wave per node)
__global__ void k_final(const float* __restrict__ y, const float* __restrict__ stats,
                        const float* __restrict__ gma, const float* __restrict__ bta,
                        const float* __restrict__ lw, const float* __restrict__ lb,
                        float* __restrict__ out, int N) {
    int lane = threadIdx.x & 63;
    int wave = (blockIdx.x * blockDim.x + threadIdx.x) >> 6;
    if (wave >= N) return;
    float invN = 1.0f / (float)N;
    float mean = stats[lane] * invN;
    float var  = stats[64 + lane] * invN - mean * mean;   // biased var
    float istd = rsqrtf(var + BN_EPS);
    float v = y[wave * 64 + lane];
    float t = (v - mean) * istd * gma[lane] + bta[lane];
    float p = t * lw[lane];
    for (int off = 32; off > 0; off >>= 1)
        p += __shfl_down(p, off, 64);
    if (lane == 0) out[wave] = p + lb[0];
}

extern "C" void kernel_launch(void* const* d_in, const int* in_sizes, int n_in,
                              void* d_out, int out_size, void* d_ws, size_t ws_size,
                              hipStream_t stream) {
    const float* x     = (const float*)d_in[0];
    const int*   ei    = (const int*)d_in[1];
    const float* ew    = (const float*)d_in[2];
    const float* Wz    = (const float*)d_in[3];
    const float* bz    = (const float*)d_in[4];
    // d_in[5] = Wr, d_in[6] = br : provably unused (H0 == 0)
    const float* Wh    = (const float*)d_in[7];
    const float* bhv   = (const float*)d_in[8];
    const float* gcn_w = (const float*)d_in[9];
    const float* gcn_b = (const float*)d_in[10];
    const float* gma   = (const float*)d_in[11];
    const float* bta   = (const float*)d_in[12];
    const float* lw    = (const float*)d_in[13];
    const float* lb    = (const float*)d_in[14];
    float* out = (float*)d_out;

    const int N = in_sizes[0] / 32;
    const int E = in_sizes[2];
    const int* row = ei;
    const int* col = ei + E;
    const int NB = (N + 255) / 256;       // 196 <= 256

    // workspace layout (4-byte words)
    float* ws      = (float*)d_ws;
    float* deg_out = ws;                              // N f
    float* deg_in  = ws + N;                          // N f
    int*   cnt_col = (int*)(ws + 2 * (size_t)N);      // N i
    int*   cnt_row = (int*)(ws + 3 * (size_t)N);      // N i
    int*   cur_col = (int*)(ws + 4 * (size_t)N);      // N i
    int*   cur_row = (int*)(ws + 5 * (size_t)N);      // N i
    float* stats   = ws + 6 * (size_t)N;              // 128 f
    int*   bsum    = (int*)(ws + 6 * (size_t)N + 128);// 512 i  <- end of zero region
    size_t Z0      = 6 * (size_t)N + 640;
    int*   off_col = (int*)(ws + Z0);                 // N i
    int*   off_row = (int*)(ws + Z0 + N);             // N i
    float* dis     = ws + Z0 + 2 * (size_t)N;         // N f
    float* txo1    = ws + Z0 + 3 * (size_t)N;         // 32N
    float* txi1    = txo1 + 32 * (size_t)N;           // 32N
    float* txo2    = txi1 + 32 * (size_t)N;           // 32N
    float* txi2    = txo2 + 32 * (size_t)N;           // 32N
    int2*  ent_col = (int2*)(txi2 + 32 * (size_t)N);  // E int2 (2E words)
    int2*  ent_row = (int2*)((float*)ent_col + 2 * (size_t)E); // E int2
    float* Zbuf    = (float*)ent_row;                 // 64N, overlays ent_row (dead after hops)
    float* xw      = Zbuf + 64 * (size_t)N;           // 64N
    float* ybuf    = txo1;                            // 64N, overlays txo1+txi1 (dead after k_hxw)

    size_t zero_bytes = (6 * (size_t)N + 640) * sizeof(float);
    hipMemsetAsync(d_ws, 0, zero_bytes, stream);

    int be = (E + 255) / 256;
    k_deg2 <<<be, 256, 0, stream>>>(row, col, ew, deg_out, deg_in, cnt_col, cnt_row, E);
    k_scan1<<<2 * NB, 256, 0, stream>>>(cnt_col, cnt_row, bsum, NB, N);
    k_scan2<<<2, 256, 0, stream>>>(bsum);
    k_scan3<<<2 * NB, 256, 0, stream>>>(cnt_col, cnt_row, bsum, off_col, off_row, NB, N);
    k_dis  <<<NB, 256, 0, stream>>>(cnt_col, dis, N);
    k_fill <<<be, 256, 0, stream>>>(row, col, ew, deg_out, deg_in,
                                    off_col, off_row, cur_col, cur_row,
                                    ent_col, ent_row, E);

    int bhop = (2 * N * 32 + 255) / 256;
    k_hop_gather<<<bhop, 256, 0, stream>>>(ent_col, ent_row, off_col, off_row,
                                           cnt_col, cnt_row, x, x, txo1, txi1, N);
    k_hop_gather<<<bhop, 256, 0, stream>>>(ent_col, ent_row, off_col, off_row,
                                           cnt_col, cnt_row, txo1, txi1, txo2, txi2, N);

    k_z  <<<1024, 256, 0, stream>>>(x, txo1, txi1, txo2, txi2, Wz, bz, Zbuf, N);
    k_hxw<<<512, 256, 0, stream>>>(x, txo1, txi1, txo2, txi2, Wh, bhv, gcn_w, Zbuf, xw, N);

    k_gcn_fused<<<512, 256, 0, stream>>>(ent_col, off_col, cnt_col, dis, xw,
                                         gcn_b, ybuf, stats, N);
    k_final<<<(N + 3) / 4, 256, 0, stream>>>(ybuf, stats, gma, bta, lw, lb, out, N);
}

// Round 5
// 801.981 us; speedup vs baseline: 2.2309x; 1.2888x over previous
//
#include <hip/hip_runtime.h>
#include <math.h>

// DCRNN (1 step, H0=0) + GCN + BN + Linear. N=50000, F=32, H=64, K=3, E=800000.
//
// Algebra: H0==0 => R gate unused; hidden half of XH stays zero through hops,
// so only W[:,:,:32,:] matters. F = [x, To1, Ti1, To2, Ti2] (N x 160),
//   Z = sigmoid(F@WcZ + bz), H = (1-Z)*tanh(F@WcH + bh), xw = H@gcn_w.
// R5: k_z + k_hxw fused into one tiled GEMM kernel k_zh. R4's dot32 was
// 1 LDS b32 per FMA -> LDS-issue bound (234us, VALUBusy 17%). k_zh: A-tile in
// LDS read via wave-uniform broadcast b128 (16 nodes/thread-group), weights
// chunk-streamed; FMA:LDS ~ 5:1, both gates in one pass, gcn matmul fused.

#define BN_EPS 1e-5f

// ---- histogram: weighted degrees (float) + edge counts (int) ----------------
__global__ void k_deg2(const int* __restrict__ row, const int* __restrict__ col,
                       const float* __restrict__ ew,
                       float* __restrict__ deg_out, float* __restrict__ deg_in,
                       int* __restrict__ cnt_col, int* __restrict__ cnt_row, int E) {
    int e = blockIdx.x * blockDim.x + threadIdx.x;
    if (e >= E) return;
    int r = row[e], c = col[e];
    float w = ew[e];
    atomicAdd(&deg_out[r], w);
    atomicAdd(&deg_in[c], w);
    atomicAdd(&cnt_col[c], 1);
    atomicAdd(&cnt_row[r], 1);
}

// ---- 3-pass exclusive scan of cnt_col / cnt_row into off_col / off_row ------
__device__ int block_scan_excl(int v, int tid, int* buf) {
    buf[tid] = v; __syncthreads();
    for (int d = 1; d < 256; d <<= 1) {
        int t = buf[tid];
        int add = (tid >= d) ? buf[tid - d] : 0;
        __syncthreads();
        buf[tid] = t + add;
        __syncthreads();
    }
    return buf[tid] - v;   // exclusive prefix
}

// pass 1: per-256-chunk totals. grid = 2*NB blocks; array a = blk/NB.
__global__ void k_scan1(const int* __restrict__ cnt_col, const int* __restrict__ cnt_row,
                        int* __restrict__ bsum, int NB, int N) {
    __shared__ int buf[256];
    int a = blockIdx.x / NB, blk = blockIdx.x % NB;
    const int* cnt = a == 0 ? cnt_col : cnt_row;
    int i = blk * 256 + threadIdx.x;
    int v = (i < N) ? cnt[i] : 0;
    int ex = block_scan_excl(v, threadIdx.x, buf);
    if (threadIdx.x == 255) bsum[a * 256 + blk] = ex + v;
}

// pass 2: scan the block totals (NB<=256). grid = 2 blocks.
__global__ void k_scan2(int* __restrict__ bsum) {
    __shared__ int buf[256];
    int a = blockIdx.x;
    int v = bsum[a * 256 + threadIdx.x];   // zero-initialized beyond NB
    int ex = block_scan_excl(v, threadIdx.x, buf);
    bsum[a * 256 + threadIdx.x] = ex;
}

// pass 3: final offsets. grid = 2*NB blocks.
__global__ void k_scan3(const int* __restrict__ cnt_col, const int* __restrict__ cnt_row,
                        const int* __restrict__ bsum,
                        int* __restrict__ off_col, int* __restrict__ off_row,
                        int NB, int N) {
    __shared__ int buf[256];
    int a = blockIdx.x / NB, blk = blockIdx.x % NB;
    const int* cnt = a == 0 ? cnt_col : cnt_row;
    int* off = a == 0 ? off_col : off_row;
    int i = blk * 256 + threadIdx.x;
    int v = (i < N) ? cnt[i] : 0;
    int ex = block_scan_excl(v, threadIdx.x, buf);
    if (i < N) off[i] = bsum[a * 256 + blk] + ex;
}

// dis[i] = rsqrt(#in-edges + 1)  (+1 = self loop)
__global__ void k_dis(const int* __restrict__ cnt_col, float* __restrict__ dis, int N) {
    int i = blockIdx.x * blockDim.x + threadIdx.x;
    if (i >= N) return;
    dis[i] = rsqrtf((float)cnt_col[i] + 1.0f);
}

// fill both CSRs: ent_col[off_col[c]+slot] = (row, w_out); ent_row: (col, w_in)
__global__ void k_fill(const int* __restrict__ row, const int* __restrict__ col,
                       const float* __restrict__ ew,
                       const float* __restrict__ deg_out, const float* __restrict__ deg_in,
                       const int* __restrict__ off_col, const int* __restrict__ off_row,
                       int* __restrict__ cur_col, int* __restrict__ cur_row,
                       int2* __restrict__ ent_col, int2* __restrict__ ent_row, int E) {
    int e = blockIdx.x * blockDim.x + threadIdx.x;
    if (e >= E) return;
    int r = row[e], c = col[e];
    float w = ew[e];
    float dO = deg_out[r], dI = deg_in[c];
    float wout = dO > 0.f ? w / dO : 0.f;
    float win  = dI > 0.f ? w / dI : 0.f;
    int sc = atomicAdd(&cur_col[c], 1);
    ent_col[off_col[c] + sc] = make_int2(r, __float_as_int(wout));
    int sr = atomicAdd(&cur_row[r], 1);
    ent_row[off_row[r] + sr] = make_int2(c, __float_as_int(win));
}

// one diffusion hop, both directions, gather form. half-wave (32 lanes) = one
// (dest,dir); lane = feature.
__global__ void k_hop_gather(const int2* __restrict__ ent_col, const int2* __restrict__ ent_row,
                             const int* __restrict__ off_col, const int* __restrict__ off_row,
                             const int* __restrict__ cnt_col, const int* __restrict__ cnt_row,
                             const float* __restrict__ So, const float* __restrict__ Si,
                             float* __restrict__ Do, float* __restrict__ Di, int N) {
    int t = blockIdx.x * blockDim.x + threadIdx.x;
    int f = t & 31;
    int p = t >> 5;
    if (p >= 2 * N) return;
    const int2* ent; const float* S; float* D;
    int d, base, cnt;
    if (p < N) {
        d = p; ent = ent_col; S = So; D = Do;
        base = off_col[d]; cnt = cnt_col[d];
    } else {
        d = p - N; ent = ent_row; S = Si; D = Di;
        base = off_row[d]; cnt = cnt_row[d];
    }
    float acc = 0.f;
    for (int j = 0; j < cnt; ++j) {
        int2 e8 = ent[base + j];
        acc += __int_as_float(e8.y) * S[e8.x * 32 + f];
    }
    D[d * 32 + f] = acc;
}

// ---- fused dual-gate GEMM + gcn matmul --------------------------------------
// Block = 256 threads, 64-node tile. Thread (g = tid>>6, c = tid&63) owns
// nodes [g*16, g*16+16) x channel c. A-tile reads are wave-uniform broadcasts.
__global__ __launch_bounds__(256) void k_zh(
    const float* __restrict__ x, const float* __restrict__ txo1,
    const float* __restrict__ txi1, const float* __restrict__ txo2,
    const float* __restrict__ txi2,
    const float* __restrict__ Wz, const float* __restrict__ bz,
    const float* __restrict__ Wh, const float* __restrict__ bh,
    const float* __restrict__ gcn_w,
    float* __restrict__ xw, int N) {
    __shared__ float A[64 * 160];      // 40 KB: [node][k], k contiguous
    __shared__ float wbuf[2048];       // 8 KB: wz chunk [16x64] + wh chunk [16x64]
    int tid = threadIdx.x;
    int c = tid & 63;
    int g = tid >> 6;
    int n0 = blockIdx.x * 64;

    // stage A-tile (zeros for tail nodes)
#define STAGE(ARR, K0)                                                          \
    for (int j = tid; j < 512; j += 256) {                                      \
        int n = j >> 3, q = j & 7; int gi = n0 + n;                             \
        float4 v = (gi < N) ? *(const float4*)((ARR) + (size_t)gi * 32 + q * 4) \
                            : make_float4(0.f, 0.f, 0.f, 0.f);                  \
        *(float4*)&A[n * 160 + (K0) + q * 4] = v;                               \
    }
    STAGE(x, 0) STAGE(txo1, 32) STAGE(txi1, 64) STAGE(txo2, 96) STAGE(txi2, 128)
#undef STAGE

    float az0=0,az1=0,az2=0,az3=0,az4=0,az5=0,az6=0,az7=0,
          az8=0,az9=0,az10=0,az11=0,az12=0,az13=0,az14=0,az15=0;
    float ah0=0,ah1=0,ah2=0,ah3=0,ah4=0,ah5=0,ah6=0,ah7=0,
          ah8=0,ah9=0,ah10=0,ah11=0,ah12=0,ah13=0,ah14=0,ah15=0;

    for (int ck = 0; ck < 10; ++ck) {
        __syncthreads();   // wbuf free (and A ready on first iter)
        // stage combined-weight chunk rows [ck*16, ck*16+16) for both gates
        for (int j = tid; j < 1024; j += 256) {
            int kl = j >> 6, cc = j & 63;
            int k = ck * 16 + kl;
            int blk = k >> 5, r = k & 31;
            float vz, vh;
            if (blk == 0) {
                vz = Wz[r * 64 + cc] + Wz[(288 + r) * 64 + cc];
                vh = Wh[r * 64 + cc] + Wh[(288 + r) * 64 + cc];
            } else {
                int kk = (blk + 1) >> 1, dd = (blk + 1) & 1;
                int off = ((dd * 3 + kk) * 96 + r) * 64 + cc;
                vz = Wz[off]; vh = Wh[off];
            }
            wbuf[j] = vz; wbuf[1024 + j] = vh;
        }
        __syncthreads();
#pragma unroll
        for (int k4 = 0; k4 < 4; ++k4) {
            float z0 = wbuf[(k4 * 4 + 0) * 64 + c];
            float z1 = wbuf[(k4 * 4 + 1) * 64 + c];
            float z2 = wbuf[(k4 * 4 + 2) * 64 + c];
            float z3 = wbuf[(k4 * 4 + 3) * 64 + c];
            float h0 = wbuf[1024 + (k4 * 4 + 0) * 64 + c];
            float h1 = wbuf[1024 + (k4 * 4 + 1) * 64 + c];
            float h2 = wbuf[1024 + (k4 * 4 + 2) * 64 + c];
            float h3 = wbuf[1024 + (k4 * 4 + 3) * 64 + c];
            const float* Ab = &A[g * 16 * 160 + ck * 16 + k4 * 4];
#define ROW(nn, AZ, AH) {                                                   \
            float4 a = *(const float4*)(Ab + (nn) * 160);                   \
            AZ += a.x * z0 + a.y * z1 + a.z * z2 + a.w * z3;                \
            AH += a.x * h0 + a.y * h1 + a.z * h2 + a.w * h3; }
            ROW(0, az0, ah0)   ROW(1, az1, ah1)   ROW(2, az2, ah2)   ROW(3, az3, ah3)
            ROW(4, az4, ah4)   ROW(5, az5, ah5)   ROW(6, az6, ah6)   ROW(7, az7, ah7)
            ROW(8, az8, ah8)   ROW(9, az9, ah9)   ROW(10, az10, ah10) ROW(11, az11, ah11)
            ROW(12, az12, ah12) ROW(13, az13, ah13) ROW(14, az14, ah14) ROW(15, az15, ah15)
#undef ROW
        }
    }

    // epilogue: h = (1 - sigmoid(zpre)) * tanh(hpre)
    float bzc = bz[c], bhc = bh[c];
#define EPI(AZ, AH) { float zz = 1.f / (1.f + expf(-((AZ) + bzc)));         \
                      AH = (1.f - zz) * tanhf((AH) + bhc); }
    EPI(az0, ah0) EPI(az1, ah1) EPI(az2, ah2) EPI(az3, ah3)
    EPI(az4, ah4) EPI(az5, ah5) EPI(az6, ah6) EPI(az7, ah7)
    EPI(az8, ah8) EPI(az9, ah9) EPI(az10, ah10) EPI(az11, ah11)
    EPI(az12, ah12) EPI(az13, ah13) EPI(az14, ah14) EPI(az15, ah15)
#undef EPI

    __syncthreads();   // all waves done reading A
    // H-tile into (reused) A region: [node][ch], stride 64
    {
        float* Ht = &A[g * 16 * 64 + c];
        Ht[0 * 64] = ah0;  Ht[1 * 64] = ah1;  Ht[2 * 64] = ah2;  Ht[3 * 64] = ah3;
        Ht[4 * 64] = ah4;  Ht[5 * 64] = ah5;  Ht[6 * 64] = ah6;  Ht[7 * 64] = ah7;
        Ht[8 * 64] = ah8;  Ht[9 * 64] = ah9;  Ht[10 * 64] = ah10; Ht[11 * 64] = ah11;
        Ht[12 * 64] = ah12; Ht[13 * 64] = ah13; Ht[14 * 64] = ah14; Ht[15 * 64] = ah15;
    }

    float b0=0,b1=0,b2=0,b3=0,b4=0,b5=0,b6=0,b7=0,
          b8=0,b9=0,b10=0,b11=0,b12=0,b13=0,b14=0,b15=0;
    for (int ck = 0; ck < 2; ++ck) {
        __syncthreads();   // H writes visible (ck=0) / wbuf free (ck=1)
        for (int j = tid; j < 2048; j += 256)
            wbuf[j] = gcn_w[ck * 2048 + j];     // rows [ck*32, ck*32+32)
        __syncthreads();
#pragma unroll
        for (int k4 = 0; k4 < 8; ++k4) {
            float g0 = wbuf[(k4 * 4 + 0) * 64 + c];
            float g1 = wbuf[(k4 * 4 + 1) * 64 + c];
            float g2 = wbuf[(k4 * 4 + 2) * 64 + c];
            float g3 = wbuf[(k4 * 4 + 3) * 64 + c];
            const float* Hb = &A[g * 16 * 64 + ck * 32 + k4 * 4];
#define ROW2(nn, B) { float4 a = *(const float4*)(Hb + (nn) * 64);          \
                      B += a.x * g0 + a.y * g1 + a.z * g2 + a.w * g3; }
            ROW2(0, b0)  ROW2(1, b1)  ROW2(2, b2)  ROW2(3, b3)
            ROW2(4, b4)  ROW2(5, b5)  ROW2(6, b6)  ROW2(7, b7)
            ROW2(8, b8)  ROW2(9, b9)  ROW2(10, b10) ROW2(11, b11)
            ROW2(12, b12) ROW2(13, b13) ROW2(14, b14) ROW2(15, b15)
#undef ROW2
        }
    }
    int nb = n0 + g * 16;
#define ST(nn, B) if (nb + (nn) < N) xw[(size_t)(nb + (nn)) * 64 + c] = B;
    ST(0, b0)  ST(1, b1)  ST(2, b2)  ST(3, b3)
    ST(4, b4)  ST(5, b5)  ST(6, b6)  ST(7, b7)
    ST(8, b8)  ST(9, b9)  ST(10, b10) ST(11, b11)
    ST(12, b12) ST(13, b13) ST(14, b14) ST(15, b15)
#undef ST
}

// GCN gather + bias + ReLU + BN stats, fused. wave = dest node, lane = channel.
__global__ void k_gcn_fused(const int2* __restrict__ ent_col,
                            const int* __restrict__ off_col, const int* __restrict__ cnt_col,
                            const float* __restrict__ dis, const float* __restrict__ xw,
                            const float* __restrict__ gcn_b,
                            float* __restrict__ y, float* __restrict__ stats, int N) {
    int lane = threadIdx.x & 63;
    int wave = (blockIdx.x * blockDim.x + threadIdx.x) >> 6;
    int nw = (gridDim.x * blockDim.x) >> 6;
    float bl = gcn_b[lane];
    float s = 0.f, s2 = 0.f;
    for (int d = wave; d < N; d += nw) {
        float dd = dis[d];
        float acc = dd * dd * xw[d * 64 + lane];
        int base = off_col[d], cnt = cnt_col[d];
        for (int j = 0; j < cnt; ++j) {
            int2 e8 = ent_col[base + j];
            acc += dis[e8.x] * dd * xw[e8.x * 64 + lane];
        }
        float v = acc + bl;
        v = v > 0.f ? v : 0.f;
        y[d * 64 + lane] = v;
        s += v; s2 += v * v;
    }
    atomicAdd(&stats[lane], s);
    atomicAdd(&stats[64 + lane], s2);
}

// out[i] = sum_f ((y[i,f]-mean)*istd*gamma + beta) * lw[f] + lb   (wave per node)
__global__ void k_final(const float* __restrict__ y, const float* __restrict__ stats,
                        const float* __restrict__ gma, const float* __restrict__ bta,
                        const float* __restrict__ lw, const float* __restrict__ lb,
                        float* __restrict__ out, int N) {
    int lane = threadIdx.x & 63;
    int wave = (blockIdx.x * blockDim.x + threadIdx.x) >> 6;
    if (wave >= N) return;
    float invN = 1.0f / (float)N;
    float mean = stats[lane] * invN;
    float var  = stats[64 + lane] * invN - mean * mean;   // biased var
    float istd = rsqrtf(var + BN_EPS);
    float v = y[wave * 64 + lane];
    float t = (v - mean) * istd * gma[lane] + bta[lane];
    float p = t * lw[lane];
    for (int off = 32; off > 0; off >>= 1)
        p += __shfl_down(p, off, 64);
    if (lane == 0) out[wave] = p + lb[0];
}

extern "C" void kernel_launch(void* const* d_in, const int* in_sizes, int n_in,
                              void* d_out, int out_size, void* d_ws, size_t ws_size,
                              hipStream_t stream) {
    const float* x     = (const float*)d_in[0];
    const int*   ei    = (const int*)d_in[1];
    const float* ew    = (const float*)d_in[2];
    const float* Wz    = (const float*)d_in[3];
    const float* bz    = (const float*)d_in[4];
    // d_in[5] = Wr, d_in[6] = br : provably unused (H0 == 0)
    const float* Wh    = (const float*)d_in[7];
    const float* bhv   = (const float*)d_in[8];
    const float* gcn_w = (const float*)d_in[9];
    const float* gcn_b = (const float*)d_in[10];
    const float* gma   = (const float*)d_in[11];
    const float* bta   = (const float*)d_in[12];
    const float* lw    = (const float*)d_in[13];
    const float* lb    = (const float*)d_in[14];
    float* out = (float*)d_out;

    const int N = in_sizes[0] / 32;
    const int E = in_sizes[2];
    const int* row = ei;
    const int* col = ei + E;
    const int NB = (N + 255) / 256;       // 196 <= 256

    // workspace layout (4-byte words) — same as R4; xw sits where Zbuf was.
    float* ws      = (float*)d_ws;
    float* deg_out = ws;                              // N f
    float* deg_in  = ws + N;                          // N f
    int*   cnt_col = (int*)(ws + 2 * (size_t)N);      // N i
    int*   cnt_row = (int*)(ws + 3 * (size_t)N);      // N i
    int*   cur_col = (int*)(ws + 4 * (size_t)N);      // N i
    int*   cur_row = (int*)(ws + 5 * (size_t)N);      // N i
    float* stats   = ws + 6 * (size_t)N;              // 128 f
    int*   bsum    = (int*)(ws + 6 * (size_t)N + 128);// 512 i  <- end of zero region
    size_t Z0      = 6 * (size_t)N + 640;
    int*   off_col = (int*)(ws + Z0);                 // N i
    int*   off_row = (int*)(ws + Z0 + N);             // N i
    float* dis     = ws + Z0 + 2 * (size_t)N;         // N f
    float* txo1    = ws + Z0 + 3 * (size_t)N;         // 32N
    float* txi1    = txo1 + 32 * (size_t)N;           // 32N
    float* txo2    = txi1 + 32 * (size_t)N;           // 32N
    float* txi2    = txo2 + 32 * (size_t)N;           // 32N
    int2*  ent_col = (int2*)(txi2 + 32 * (size_t)N);  // E int2 (2E words)
    int2*  ent_row = (int2*)((float*)ent_col + 2 * (size_t)E); // E int2
    float* xw      = (float*)ent_row;                 // 64N, overlays ent_row (dead after hops)
    float* ybuf    = txo1;                            // 64N, overlays txo1+txi1 (dead after k_zh)

    size_t zero_bytes = (6 * (size_t)N + 640) * sizeof(float);
    hipMemsetAsync(d_ws, 0, zero_bytes, stream);

    int be = (E + 255) / 256;
    k_deg2 <<<be, 256, 0, stream>>>(row, col, ew, deg_out, deg_in, cnt_col, cnt_row, E);
    k_scan1<<<2 * NB, 256, 0, stream>>>(cnt_col, cnt_row, bsum, NB, N);
    k_scan2<<<2, 256, 0, stream>>>(bsum);
    k_scan3<<<2 * NB, 256, 0, stream>>>(cnt_col, cnt_row, bsum, off_col, off_row, NB, N);
    k_dis  <<<NB, 256, 0, stream>>>(cnt_col, dis, N);
    k_fill <<<be, 256, 0, stream>>>(row, col, ew, deg_out, deg_in,
                                    off_col, off_row, cur_col, cur_row,
                                    ent_col, ent_row, E);

    int bhop = (2 * N * 32 + 255) / 256;
    k_hop_gather<<<bhop, 256, 0, stream>>>(ent_col, ent_row, off_col, off_row,
                                           cnt_col, cnt_row, x, x, txo1, txi1, N);
    k_hop_gather<<<bhop, 256, 0, stream>>>(ent_col, ent_row, off_col, off_row,
                                           cnt_col, cnt_row, txo1, txi1, txo2, txi2, N);

    k_zh<<<(N + 63) / 64, 256, 0, stream>>>(x, txo1, txi1, txo2, txi2,
                                            Wz, bz, Wh, bhv, gcn_w, xw, N);

    k_gcn_fused<<<512, 256, 0, stream>>>(ent_col, off_col, cnt_col, dis, xw,
                                         gcn_b, ybuf, stats, N);
    k_final<<<(N + 3) / 4, 256, 0, stream>>>(ybuf, stats, gma, bta, lw, lb, out, N);
}

// Round 6
// 594.196 us; speedup vs baseline: 3.0110x; 1.3497x over previous
//
#include <hip/hip_runtime.h>
#include <math.h>

// DCRNN (1 step, H0=0) + GCN + BN + Linear. N=50000, F=32, H=64, K=3, E=800000.
//
// Algebra: H0==0 => R gate unused; hidden half of XH stays zero through hops,
// so only W[:,:,:32,:] matters. F = [x, To1, Ti1, To2, Ti2] (N x 160),
//   Z = sigmoid(F@WcZ + bz), H = (1-Z)*tanh(F@WcH + bh), xw = H@gcn_w.
// R6: k_gcn_fused was latency-bound at 8 waves/CU (grid=512: occ 19.7%,
// VALU 6%, HBM 7%). Grid -> 1600 + LDS stats reduction + 2x edge-loop
// unroll (two independent gather chains in flight). Hops unrolled 2x too.

#define BN_EPS 1e-5f

// ---- histogram: weighted degrees (float) + edge counts (int) ----------------
__global__ void k_deg2(const int* __restrict__ row, const int* __restrict__ col,
                       const float* __restrict__ ew,
                       float* __restrict__ deg_out, float* __restrict__ deg_in,
                       int* __restrict__ cnt_col, int* __restrict__ cnt_row, int E) {
    int e = blockIdx.x * blockDim.x + threadIdx.x;
    if (e >= E) return;
    int r = row[e], c = col[e];
    float w = ew[e];
    atomicAdd(&deg_out[r], w);
    atomicAdd(&deg_in[c], w);
    atomicAdd(&cnt_col[c], 1);
    atomicAdd(&cnt_row[r], 1);
}

// ---- 3-pass exclusive scan of cnt_col / cnt_row into off_col / off_row ------
__device__ int block_scan_excl(int v, int tid, int* buf) {
    buf[tid] = v; __syncthreads();
    for (int d = 1; d < 256; d <<= 1) {
        int t = buf[tid];
        int add = (tid >= d) ? buf[tid - d] : 0;
        __syncthreads();
        buf[tid] = t + add;
        __syncthreads();
    }
    return buf[tid] - v;   // exclusive prefix
}

// pass 1: per-256-chunk totals. grid = 2*NB blocks; array a = blk/NB.
__global__ void k_scan1(const int* __restrict__ cnt_col, const int* __restrict__ cnt_row,
                        int* __restrict__ bsum, int NB, int N) {
    __shared__ int buf[256];
    int a = blockIdx.x / NB, blk = blockIdx.x % NB;
    const int* cnt = a == 0 ? cnt_col : cnt_row;
    int i = blk * 256 + threadIdx.x;
    int v = (i < N) ? cnt[i] : 0;
    int ex = block_scan_excl(v, threadIdx.x, buf);
    if (threadIdx.x == 255) bsum[a * 256 + blk] = ex + v;
}

// pass 2: scan the block totals (NB<=256). grid = 2 blocks.
__global__ void k_scan2(int* __restrict__ bsum) {
    __shared__ int buf[256];
    int a = blockIdx.x;
    int v = bsum[a * 256 + threadIdx.x];   // zero-initialized beyond NB
    int ex = block_scan_excl(v, threadIdx.x, buf);
    bsum[a * 256 + threadIdx.x] = ex;
}

// pass 3: final offsets. grid = 2*NB blocks.
__global__ void k_scan3(const int* __restrict__ cnt_col, const int* __restrict__ cnt_row,
                        const int* __restrict__ bsum,
                        int* __restrict__ off_col, int* __restrict__ off_row,
                        int NB, int N) {
    __shared__ int buf[256];
    int a = blockIdx.x / NB, blk = blockIdx.x % NB;
    const int* cnt = a == 0 ? cnt_col : cnt_row;
    int* off = a == 0 ? off_col : off_row;
    int i = blk * 256 + threadIdx.x;
    int v = (i < N) ? cnt[i] : 0;
    int ex = block_scan_excl(v, threadIdx.x, buf);
    if (i < N) off[i] = bsum[a * 256 + blk] + ex;
}

// dis[i] = rsqrt(#in-edges + 1)  (+1 = self loop)
__global__ void k_dis(const int* __restrict__ cnt_col, float* __restrict__ dis, int N) {
    int i = blockIdx.x * blockDim.x + threadIdx.x;
    if (i >= N) return;
    dis[i] = rsqrtf((float)cnt_col[i] + 1.0f);
}

// fill both CSRs: ent_col[off_col[c]+slot] = (row, w_out); ent_row: (col, w_in)
__global__ void k_fill(const int* __restrict__ row, const int* __restrict__ col,
                       const float* __restrict__ ew,
                       const float* __restrict__ deg_out, const float* __restrict__ deg_in,
                       const int* __restrict__ off_col, const int* __restrict__ off_row,
                       int* __restrict__ cur_col, int* __restrict__ cur_row,
                       int2* __restrict__ ent_col, int2* __restrict__ ent_row, int E) {
    int e = blockIdx.x * blockDim.x + threadIdx.x;
    if (e >= E) return;
    int r = row[e], c = col[e];
    float w = ew[e];
    float dO = deg_out[r], dI = deg_in[c];
    float wout = dO > 0.f ? w / dO : 0.f;
    float win  = dI > 0.f ? w / dI : 0.f;
    int sc = atomicAdd(&cur_col[c], 1);
    ent_col[off_col[c] + sc] = make_int2(r, __float_as_int(wout));
    int sr = atomicAdd(&cur_row[r], 1);
    ent_row[off_row[r] + sr] = make_int2(c, __float_as_int(win));
}

// one diffusion hop, both directions, gather form. half-wave (32 lanes) = one
// (dest,dir); lane = feature. Edge loop unrolled 2x for MLP.
__global__ void k_hop_gather(const int2* __restrict__ ent_col, const int2* __restrict__ ent_row,
                             const int* __restrict__ off_col, const int* __restrict__ off_row,
                             const int* __restrict__ cnt_col, const int* __restrict__ cnt_row,
                             const float* __restrict__ So, const float* __restrict__ Si,
                             float* __restrict__ Do, float* __restrict__ Di, int N) {
    int t = blockIdx.x * blockDim.x + threadIdx.x;
    int f = t & 31;
    int p = t >> 5;
    if (p >= 2 * N) return;
    const int2* ent; const float* S; float* D;
    int d, base, cnt;
    if (p < N) {
        d = p; ent = ent_col; S = So; D = Do;
        base = off_col[d]; cnt = cnt_col[d];
    } else {
        d = p - N; ent = ent_row; S = Si; D = Di;
        base = off_row[d]; cnt = cnt_row[d];
    }
    float acc = 0.f;
    int j = 0;
    for (; j + 1 < cnt; j += 2) {
        int2 e0 = ent[base + j];
        int2 e1 = ent[base + j + 1];
        float v0 = S[e0.x * 32 + f];
        float v1 = S[e1.x * 32 + f];
        acc += __int_as_float(e0.y) * v0 + __int_as_float(e1.y) * v1;
    }
    if (j < cnt) {
        int2 e0 = ent[base + j];
        acc += __int_as_float(e0.y) * S[e0.x * 32 + f];
    }
    D[d * 32 + f] = acc;
}

// ---- fused dual-gate GEMM + gcn matmul --------------------------------------
// Block = 256 threads, 64-node tile. Thread (g = tid>>6, c = tid&63) owns
// nodes [g*16, g*16+16) x channel c. A-tile reads are wave-uniform broadcasts.
__global__ __launch_bounds__(256) void k_zh(
    const float* __restrict__ x, const float* __restrict__ txo1,
    const float* __restrict__ txi1, const float* __restrict__ txo2,
    const float* __restrict__ txi2,
    const float* __restrict__ Wz, const float* __restrict__ bz,
    const float* __restrict__ Wh, const float* __restrict__ bh,
    const float* __restrict__ gcn_w,
    float* __restrict__ xw, int N) {
    __shared__ float A[64 * 160];      // 40 KB: [node][k], k contiguous
    __shared__ float wbuf[2048];       // 8 KB: wz chunk [16x64] + wh chunk [16x64]
    int tid = threadIdx.x;
    int c = tid & 63;
    int g = tid >> 6;
    int n0 = blockIdx.x * 64;

    // stage A-tile (zeros for tail nodes)
#define STAGE(ARR, K0)                                                          \
    for (int j = tid; j < 512; j += 256) {                                      \
        int n = j >> 3, q = j & 7; int gi = n0 + n;                             \
        float4 v = (gi < N) ? *(const float4*)((ARR) + (size_t)gi * 32 + q * 4) \
                            : make_float4(0.f, 0.f, 0.f, 0.f);                  \
        *(float4*)&A[n * 160 + (K0) + q * 4] = v;                               \
    }
    STAGE(x, 0) STAGE(txo1, 32) STAGE(txi1, 64) STAGE(txo2, 96) STAGE(txi2, 128)
#undef STAGE

    float az0=0,az1=0,az2=0,az3=0,az4=0,az5=0,az6=0,az7=0,
          az8=0,az9=0,az10=0,az11=0,az12=0,az13=0,az14=0,az15=0;
    float ah0=0,ah1=0,ah2=0,ah3=0,ah4=0,ah5=0,ah6=0,ah7=0,
          ah8=0,ah9=0,ah10=0,ah11=0,ah12=0,ah13=0,ah14=0,ah15=0;

    for (int ck = 0; ck < 10; ++ck) {
        __syncthreads();   // wbuf free (and A ready on first iter)
        // stage combined-weight chunk rows [ck*16, ck*16+16) for both gates
        for (int j = tid; j < 1024; j += 256) {
            int kl = j >> 6, cc = j & 63;
            int k = ck * 16 + kl;
            int blk = k >> 5, r = k & 31;
            float vz, vh;
            if (blk == 0) {
                vz = Wz[r * 64 + cc] + Wz[(288 + r) * 64 + cc];
                vh = Wh[r * 64 + cc] + Wh[(288 + r) * 64 + cc];
            } else {
                int kk = (blk + 1) >> 1, dd = (blk + 1) & 1;
                int off = ((dd * 3 + kk) * 96 + r) * 64 + cc;
                vz = Wz[off]; vh = Wh[off];
            }
            wbuf[j] = vz; wbuf[1024 + j] = vh;
        }
        __syncthreads();
#pragma unroll
        for (int k4 = 0; k4 < 4; ++k4) {
            float z0 = wbuf[(k4 * 4 + 0) * 64 + c];
            float z1 = wbuf[(k4 * 4 + 1) * 64 + c];
            float z2 = wbuf[(k4 * 4 + 2) * 64 + c];
            float z3 = wbuf[(k4 * 4 + 3) * 64 + c];
            float h0 = wbuf[1024 + (k4 * 4 + 0) * 64 + c];
            float h1 = wbuf[1024 + (k4 * 4 + 1) * 64 + c];
            float h2 = wbuf[1024 + (k4 * 4 + 2) * 64 + c];
            float h3 = wbuf[1024 + (k4 * 4 + 3) * 64 + c];
            const float* Ab = &A[g * 16 * 160 + ck * 16 + k4 * 4];
#define ROW(nn, AZ, AH) {                                                   \
            float4 a = *(const float4*)(Ab + (nn) * 160);                   \
            AZ += a.x * z0 + a.y * z1 + a.z * z2 + a.w * z3;                \
            AH += a.x * h0 + a.y * h1 + a.z * h2 + a.w * h3; }
            ROW(0, az0, ah0)   ROW(1, az1, ah1)   ROW(2, az2, ah2)   ROW(3, az3, ah3)
            ROW(4, az4, ah4)   ROW(5, az5, ah5)   ROW(6, az6, ah6)   ROW(7, az7, ah7)
            ROW(8, az8, ah8)   ROW(9, az9, ah9)   ROW(10, az10, ah10) ROW(11, az11, ah11)
            ROW(12, az12, ah12) ROW(13, az13, ah13) ROW(14, az14, ah14) ROW(15, az15, ah15)
#undef ROW
        }
    }

    // epilogue: h = (1 - sigmoid(zpre)) * tanh(hpre)
    float bzc = bz[c], bhc = bh[c];
#define EPI(AZ, AH) { float zz = 1.f / (1.f + expf(-((AZ) + bzc)));         \
                      AH = (1.f - zz) * tanhf((AH) + bhc); }
    EPI(az0, ah0) EPI(az1, ah1) EPI(az2, ah2) EPI(az3, ah3)
    EPI(az4, ah4) EPI(az5, ah5) EPI(az6, ah6) EPI(az7, ah7)
    EPI(az8, ah8) EPI(az9, ah9) EPI(az10, ah10) EPI(az11, ah11)
    EPI(az12, ah12) EPI(az13, ah13) EPI(az14, ah14) EPI(az15, ah15)
#undef EPI

    __syncthreads();   // all waves done reading A
    // H-tile into (reused) A region: [node][ch], stride 64
    {
        float* Ht = &A[g * 16 * 64 + c];
        Ht[0 * 64] = ah0;  Ht[1 * 64] = ah1;  Ht[2 * 64] = ah2;  Ht[3 * 64] = ah3;
        Ht[4 * 64] = ah4;  Ht[5 * 64] = ah5;  Ht[6 * 64] = ah6;  Ht[7 * 64] = ah7;
        Ht[8 * 64] = ah8;  Ht[9 * 64] = ah9;  Ht[10 * 64] = ah10; Ht[11 * 64] = ah11;
        Ht[12 * 64] = ah12; Ht[13 * 64] = ah13; Ht[14 * 64] = ah14; Ht[15 * 64] = ah15;
    }

    float b0=0,b1=0,b2=0,b3=0,b4=0,b5=0,b6=0,b7=0,
          b8=0,b9=0,b10=0,b11=0,b12=0,b13=0,b14=0,b15=0;
    for (int ck = 0; ck < 2; ++ck) {
        __syncthreads();   // H writes visible (ck=0) / wbuf free (ck=1)
        for (int j = tid; j < 2048; j += 256)
            wbuf[j] = gcn_w[ck * 2048 + j];     // rows [ck*32, ck*32+32)
        __syncthreads();
#pragma unroll
        for (int k4 = 0; k4 < 8; ++k4) {
            float g0 = wbuf[(k4 * 4 + 0) * 64 + c];
            float g1 = wbuf[(k4 * 4 + 1) * 64 + c];
            float g2 = wbuf[(k4 * 4 + 2) * 64 + c];
            float g3 = wbuf[(k4 * 4 + 3) * 64 + c];
            const float* Hb = &A[g * 16 * 64 + ck * 32 + k4 * 4];
#define ROW2(nn, B) { float4 a = *(const float4*)(Hb + (nn) * 64);          \
                      B += a.x * g0 + a.y * g1 + a.z * g2 + a.w * g3; }
            ROW2(0, b0)  ROW2(1, b1)  ROW2(2, b2)  ROW2(3, b3)
            ROW2(4, b4)  ROW2(5, b5)  ROW2(6, b6)  ROW2(7, b7)
            ROW2(8, b8)  ROW2(9, b9)  ROW2(10, b10) ROW2(11, b11)
            ROW2(12, b12) ROW2(13, b13) ROW2(14, b14) ROW2(15, b15)
#undef ROW2
        }
    }
    int nb = n0 + g * 16;
#define ST(nn, B) if (nb + (nn) < N) xw[(size_t)(nb + (nn)) * 64 + c] = B;
    ST(0, b0)  ST(1, b1)  ST(2, b2)  ST(3, b3)
    ST(4, b4)  ST(5, b5)  ST(6, b6)  ST(7, b7)
    ST(8, b8)  ST(9, b9)  ST(10, b10) ST(11, b11)
    ST(12, b12) ST(13, b13) ST(14, b14) ST(15, b15)
#undef ST
}

// GCN gather + bias + ReLU + BN stats, fused. wave = dest node, lane = channel.
// 2x-unrolled edge loop; block-level LDS stats reduction (grid-scalable).
__global__ __launch_bounds__(256) void k_gcn_fused(
    const int2* __restrict__ ent_col,
    const int* __restrict__ off_col, const int* __restrict__ cnt_col,
    const float* __restrict__ dis, const float* __restrict__ xw,
    const float* __restrict__ gcn_b,
    float* __restrict__ y, float* __restrict__ stats, int N) {
    __shared__ float red[2][256];
    int lane = threadIdx.x & 63;
    int wid  = threadIdx.x >> 6;
    int wave = (blockIdx.x * blockDim.x + threadIdx.x) >> 6;
    int nw = (gridDim.x * blockDim.x) >> 6;
    float bl = gcn_b[lane];
    float s = 0.f, s2 = 0.f;
    for (int d = wave; d < N; d += nw) {
        float dd = dis[d];
        float acc = dd * dd * xw[(size_t)d * 64 + lane];
        int base = off_col[d], cnt = cnt_col[d];
        int j = 0;
        for (; j + 1 < cnt; j += 2) {
            int2 e0 = ent_col[base + j];
            int2 e1 = ent_col[base + j + 1];
            float w0 = dis[e0.x], w1 = dis[e1.x];
            float v0 = xw[(size_t)e0.x * 64 + lane];
            float v1 = xw[(size_t)e1.x * 64 + lane];
            acc += dd * (w0 * v0 + w1 * v1);
        }
        if (j < cnt) {
            int2 e0 = ent_col[base + j];
            acc += dd * dis[e0.x] * xw[(size_t)e0.x * 64 + lane];
        }
        float v = acc + bl;
        v = v > 0.f ? v : 0.f;
        y[(size_t)d * 64 + lane] = v;
        s += v; s2 += v * v;
    }
    red[0][threadIdx.x] = s;
    red[1][threadIdx.x] = s2;
    __syncthreads();
    if (wid == 0) {
        float ts  = red[0][lane] + red[0][64 + lane] + red[0][128 + lane] + red[0][192 + lane];
        float ts2 = red[1][lane] + red[1][64 + lane] + red[1][128 + lane] + red[1][192 + lane];
        atomicAdd(&stats[lane], ts);
        atomicAdd(&stats[64 + lane], ts2);
    }
}

// out[i] = sum_f ((y[i,f]-mean)*istd*gamma + beta) * lw[f] + lb   (wave per node)
__global__ void k_final(const float* __restrict__ y, const float* __restrict__ stats,
                        const float* __restrict__ gma, const float* __restrict__ bta,
                        const float* __restrict__ lw, const float* __restrict__ lb,
                        float* __restrict__ out, int N) {
    int lane = threadIdx.x & 63;
    int wave = (blockIdx.x * blockDim.x + threadIdx.x) >> 6;
    if (wave >= N) return;
    float invN = 1.0f / (float)N;
    float mean = stats[lane] * invN;
    float var  = stats[64 + lane] * invN - mean * mean;   // biased var
    float istd = rsqrtf(var + BN_EPS);
    float v = y[(size_t)wave * 64 + lane];
    float t = (v - mean) * istd * gma[lane] + bta[lane];
    float p = t * lw[lane];
    for (int off = 32; off > 0; off >>= 1)
        p += __shfl_down(p, off, 64);
    if (lane == 0) out[wave] = p + lb[0];
}

extern "C" void kernel_launch(void* const* d_in, const int* in_sizes, int n_in,
                              void* d_out, int out_size, void* d_ws, size_t ws_size,
                              hipStream_t stream) {
    const float* x     = (const float*)d_in[0];
    const int*   ei    = (const int*)d_in[1];
    const float* ew    = (const float*)d_in[2];
    const float* Wz    = (const float*)d_in[3];
    const float* bz    = (const float*)d_in[4];
    // d_in[5] = Wr, d_in[6] = br : provably unused (H0 == 0)
    const float* Wh    = (const float*)d_in[7];
    const float* bhv   = (const float*)d_in[8];
    const float* gcn_w = (const float*)d_in[9];
    const float* gcn_b = (const float*)d_in[10];
    const float* gma   = (const float*)d_in[11];
    const float* bta   = (const float*)d_in[12];
    const float* lw    = (const float*)d_in[13];
    const float* lb    = (const float*)d_in[14];
    float* out = (float*)d_out;

    const int N = in_sizes[0] / 32;
    const int E = in_sizes[2];
    const int* row = ei;
    const int* col = ei + E;
    const int NB = (N + 255) / 256;       // 196 <= 256

    // workspace layout (4-byte words)
    float* ws      = (float*)d_ws;
    float* deg_out = ws;                              // N f
    float* deg_in  = ws + N;                          // N f
    int*   cnt_col = (int*)(ws + 2 * (size_t)N);      // N i
    int*   cnt_row = (int*)(ws + 3 * (size_t)N);      // N i
    int*   cur_col = (int*)(ws + 4 * (size_t)N);      // N i
    int*   cur_row = (int*)(ws + 5 * (size_t)N);      // N i
    float* stats   = ws + 6 * (size_t)N;              // 128 f
    int*   bsum    = (int*)(ws + 6 * (size_t)N + 128);// 512 i  <- end of zero region
    size_t Z0      = 6 * (size_t)N + 640;
    int*   off_col = (int*)(ws + Z0);                 // N i
    int*   off_row = (int*)(ws + Z0 + N);             // N i
    float* dis     = ws + Z0 + 2 * (size_t)N;         // N f
    float* txo1    = ws + Z0 + 3 * (size_t)N;         // 32N
    float* txi1    = txo1 + 32 * (size_t)N;           // 32N
    float* txo2    = txi1 + 32 * (size_t)N;           // 32N
    float* txi2    = txo2 + 32 * (size_t)N;           // 32N
    int2*  ent_col = (int2*)(txi2 + 32 * (size_t)N);  // E int2 (2E words)
    int2*  ent_row = (int2*)((float*)ent_col + 2 * (size_t)E); // E int2
    float* xw      = (float*)ent_row;                 // 64N, overlays ent_row (dead after hops)
    float* ybuf    = txo1;                            // 64N, overlays txo1+txi1 (dead after k_zh)

    size_t zero_bytes = (6 * (size_t)N + 640) * sizeof(float);
    hipMemsetAsync(d_ws, 0, zero_bytes, stream);

    int be = (E + 255) / 256;
    k_deg2 <<<be, 256, 0, stream>>>(row, col, ew, deg_out, deg_in, cnt_col, cnt_row, E);
    k_scan1<<<2 * NB, 256, 0, stream>>>(cnt_col, cnt_row, bsum, NB, N);
    k_scan2<<<2, 256, 0, stream>>>(bsum);
    k_scan3<<<2 * NB, 256, 0, stream>>>(cnt_col, cnt_row, bsum, off_col, off_row, NB, N);
    k_dis  <<<NB, 256, 0, stream>>>(cnt_col, dis, N);
    k_fill <<<be, 256, 0, stream>>>(row, col, ew, deg_out, deg_in,
                                    off_col, off_row, cur_col, cur_row,
                                    ent_col, ent_row, E);

    int bhop = (2 * N * 32 + 255) / 256;
    k_hop_gather<<<bhop, 256, 0, stream>>>(ent_col, ent_row, off_col, off_row,
                                           cnt_col, cnt_row, x, x, txo1, txi1, N);
    k_hop_gather<<<bhop, 256, 0, stream>>>(ent_col, ent_row, off_col, off_row,
                                           cnt_col, cnt_row, txo1, txi1, txo2, txi2, N);

    k_zh<<<(N + 63) / 64, 256, 0, stream>>>(x, txo1, txi1, txo2, txi2,
                                            Wz, bz, Wh, bhv, gcn_w, xw, N);

    k_gcn_fused<<<1600, 256, 0, stream>>>(ent_col, off_col, cnt_col, dis, xw,
                                          gcn_b, ybuf, stats, N);
    k_final<<<(N + 3) / 4, 256, 0, stream>>>(ybuf, stats, gma, bta, lw, lb, out, N);
}

// Round 7
// 536.196 us; speedup vs baseline: 3.3367x; 1.1082x over previous
//
#include <hip/hip_runtime.h>
#include <math.h>

// DCRNN (1 step, H0=0) + GCN + BN + Linear. N=50000, F=32, H=64, K=3, E=800000.
//
// Algebra: H0==0 => R gate unused; hidden half of XH stays zero through hops,
// so only W[:,:,:32,:] matters. F = [x, To1, Ti1, To2, Ti2] (N x 160),
//   Z = sigmoid(F@WcZ + bz), H = (1-Z)*tanh(F@WcH + bh), xw = H@gcn_w.
// R7: k_deg2 (4 atomics/edge, 141us) split: k_cnt (2 int atomics) + k_degs
// (gather float degrees from CSR, no atomics). Edge normalization moved into
// node scaling: hop1 gathers do_inv-prescaled features; hop2 scales by
// inv[src] at gather; k_zh stores xws=dis*xw so gcn drops dis[src] lookup.
// Hops + gcn unrolled 4x.

#define BN_EPS 1e-5f

// ---- edge-count histograms (int) --------------------------------------------
__global__ void k_cnt(const int* __restrict__ row, const int* __restrict__ col,
                      int* __restrict__ cnt_col, int* __restrict__ cnt_row, int E) {
    int e = blockIdx.x * blockDim.x + threadIdx.x;
    if (e >= E) return;
    atomicAdd(&cnt_col[col[e]], 1);
    atomicAdd(&cnt_row[row[e]], 1);
}

// ---- 3-pass exclusive scan of cnt_col / cnt_row into off_col / off_row ------
__device__ int block_scan_excl(int v, int tid, int* buf) {
    buf[tid] = v; __syncthreads();
    for (int d = 1; d < 256; d <<= 1) {
        int t = buf[tid];
        int add = (tid >= d) ? buf[tid - d] : 0;
        __syncthreads();
        buf[tid] = t + add;
        __syncthreads();
    }
    return buf[tid] - v;   // exclusive prefix
}

__global__ void k_scan1(const int* __restrict__ cnt_col, const int* __restrict__ cnt_row,
                        int* __restrict__ bsum, int NB, int N) {
    __shared__ int buf[256];
    int a = blockIdx.x / NB, blk = blockIdx.x % NB;
    const int* cnt = a == 0 ? cnt_col : cnt_row;
    int i = blk * 256 + threadIdx.x;
    int v = (i < N) ? cnt[i] : 0;
    int ex = block_scan_excl(v, threadIdx.x, buf);
    if (threadIdx.x == 255) bsum[a * 256 + blk] = ex + v;
}

__global__ void k_scan2(int* __restrict__ bsum) {
    __shared__ int buf[256];
    int a = blockIdx.x;
    int v = bsum[a * 256 + threadIdx.x];   // zero-initialized beyond NB
    int ex = block_scan_excl(v, threadIdx.x, buf);
    bsum[a * 256 + threadIdx.x] = ex;
}

__global__ void k_scan3(const int* __restrict__ cnt_col, const int* __restrict__ cnt_row,
                        const int* __restrict__ bsum,
                        int* __restrict__ off_col, int* __restrict__ off_row,
                        int NB, int N) {
    __shared__ int buf[256];
    int a = blockIdx.x / NB, blk = blockIdx.x % NB;
    const int* cnt = a == 0 ? cnt_col : cnt_row;
    int* off = a == 0 ? off_col : off_row;
    int i = blk * 256 + threadIdx.x;
    int v = (i < N) ? cnt[i] : 0;
    int ex = block_scan_excl(v, threadIdx.x, buf);
    if (i < N) off[i] = bsum[a * 256 + blk] + ex;
}

// fill both CSRs with RAW edge weight: ent_col[...]=(row,ew); ent_row[...]=(col,ew)
__global__ void k_fill(const int* __restrict__ row, const int* __restrict__ col,
                       const float* __restrict__ ew,
                       const int* __restrict__ off_col, const int* __restrict__ off_row,
                       int* __restrict__ cur_col, int* __restrict__ cur_row,
                       int2* __restrict__ ent_col, int2* __restrict__ ent_row, int E) {
    int e = blockIdx.x * blockDim.x + threadIdx.x;
    if (e >= E) return;
    int r = row[e], c = col[e];
    int wbits = __float_as_int(ew[e]);
    int sc = atomicAdd(&cur_col[c], 1);
    ent_col[off_col[c] + sc] = make_int2(r, wbits);
    int sr = atomicAdd(&cur_row[r], 1);
    ent_row[off_row[r] + sr] = make_int2(c, wbits);
}

// per-node: deg_out = sum of out-edge weights (CSR-by-row), deg_in from CSR-by-col.
// writes do_inv, di_inv, dis. no atomics.
__global__ void k_degs(const int2* __restrict__ ent_col, const int2* __restrict__ ent_row,
                       const int* __restrict__ off_col, const int* __restrict__ cnt_col,
                       const int* __restrict__ off_row, const int* __restrict__ cnt_row,
                       float* __restrict__ do_inv, float* __restrict__ di_inv,
                       float* __restrict__ dis, int N) {
    int i = blockIdx.x * blockDim.x + threadIdx.x;
    if (i >= N) return;
    float s = 0.f;
    int b = off_row[i], c = cnt_row[i];
    for (int j = 0; j < c; ++j) s += __int_as_float(ent_row[b + j].y);
    do_inv[i] = s > 0.f ? 1.f / s : 0.f;
    s = 0.f;
    b = off_col[i]; c = cnt_col[i];
    for (int j = 0; j < c; ++j) s += __int_as_float(ent_col[b + j].y);
    di_inv[i] = s > 0.f ? 1.f / s : 0.f;
    dis[i] = rsqrtf((float)cnt_col[i] + 1.0f);
}

// xo0 = do_inv * x, xi0 = di_inv * x  (per node)
__global__ void k_pre(const float* __restrict__ x, const float* __restrict__ do_inv,
                      const float* __restrict__ di_inv,
                      float* __restrict__ xo0, float* __restrict__ xi0, int N) {
    int t = blockIdx.x * blockDim.x + threadIdx.x;
    if (t >= N * 32) return;
    int n = t >> 5;
    float v = x[t];
    xo0[t] = v * do_inv[n];
    xi0[t] = v * di_inv[n];
}

// hop 1: sources pre-scaled, entry weight = raw ew. half-wave = (dest,dir).
__global__ void k_hop1(const int2* __restrict__ ent_col, const int2* __restrict__ ent_row,
                       const int* __restrict__ off_col, const int* __restrict__ off_row,
                       const int* __restrict__ cnt_col, const int* __restrict__ cnt_row,
                       const float* __restrict__ So, const float* __restrict__ Si,
                       float* __restrict__ Do, float* __restrict__ Di, int N) {
    int t = blockIdx.x * blockDim.x + threadIdx.x;
    int f = t & 31;
    int p = t >> 5;
    if (p >= 2 * N) return;
    const int2* ent; const float* S; float* D;
    int d, base, cnt;
    if (p < N) { d = p;     ent = ent_col; S = So; D = Do; base = off_col[d]; cnt = cnt_col[d]; }
    else       { d = p - N; ent = ent_row; S = Si; D = Di; base = off_row[d]; cnt = cnt_row[d]; }
    float acc = 0.f;
    int j = 0;
    for (; j + 3 < cnt; j += 4) {
        int2 e0 = ent[base + j],     e1 = ent[base + j + 1];
        int2 e2 = ent[base + j + 2], e3 = ent[base + j + 3];
        float v0 = S[e0.x * 32 + f], v1 = S[e1.x * 32 + f];
        float v2 = S[e2.x * 32 + f], v3 = S[e3.x * 32 + f];
        acc += __int_as_float(e0.y) * v0 + __int_as_float(e1.y) * v1
             + __int_as_float(e2.y) * v2 + __int_as_float(e3.y) * v3;
    }
    for (; j < cnt; ++j) {
        int2 e0 = ent[base + j];
        acc += __int_as_float(e0.y) * S[e0.x * 32 + f];
    }
    D[d * 32 + f] = acc;
}

// hop 2: sources raw, scale by inv[src] at gather (inv = do_inv / di_inv table).
__global__ void k_hop2(const int2* __restrict__ ent_col, const int2* __restrict__ ent_row,
                       const int* __restrict__ off_col, const int* __restrict__ off_row,
                       const int* __restrict__ cnt_col, const int* __restrict__ cnt_row,
                       const float* __restrict__ So, const float* __restrict__ Si,
                       const float* __restrict__ do_inv, const float* __restrict__ di_inv,
                       float* __restrict__ Do, float* __restrict__ Di, int N) {
    int t = blockIdx.x * blockDim.x + threadIdx.x;
    int f = t & 31;
    int p = t >> 5;
    if (p >= 2 * N) return;
    const int2* ent; const float* S; const float* inv; float* D;
    int d, base, cnt;
    if (p < N) { d = p;     ent = ent_col; S = So; inv = do_inv; D = Do; base = off_col[d]; cnt = cnt_col[d]; }
    else       { d = p - N; ent = ent_row; S = Si; inv = di_inv; D = Di; base = off_row[d]; cnt = cnt_row[d]; }
    float acc = 0.f;
    int j = 0;
    for (; j + 3 < cnt; j += 4) {
        int2 e0 = ent[base + j],     e1 = ent[base + j + 1];
        int2 e2 = ent[base + j + 2], e3 = ent[base + j + 3];
        float i0 = inv[e0.x], i1 = inv[e1.x], i2 = inv[e2.x], i3 = inv[e3.x];
        float v0 = S[e0.x * 32 + f], v1 = S[e1.x * 32 + f];
        float v2 = S[e2.x * 32 + f], v3 = S[e3.x * 32 + f];
        acc += __int_as_float(e0.y) * i0 * v0 + __int_as_float(e1.y) * i1 * v1
             + __int_as_float(e2.y) * i2 * v2 + __int_as_float(e3.y) * i3 * v3;
    }
    for (; j < cnt; ++j) {
        int2 e0 = ent[base + j];
        acc += __int_as_float(e0.y) * inv[e0.x] * S[e0.x * 32 + f];
    }
    D[d * 32 + f] = acc;
}

// ---- fused dual-gate GEMM + gcn matmul; stores xws = dis * (H @ gcn_w) ------
__global__ __launch_bounds__(256) void k_zh(
    const float* __restrict__ x, const float* __restrict__ txo1,
    const float* __restrict__ txi1, const float* __restrict__ txo2,
    const float* __restrict__ txi2,
    const float* __restrict__ Wz, const float* __restrict__ bz,
    const float* __restrict__ Wh, const float* __restrict__ bh,
    const float* __restrict__ gcn_w, const float* __restrict__ dis,
    float* __restrict__ xws, int N) {
    __shared__ float A[64 * 160];      // 40 KB: [node][k], k contiguous
    __shared__ float wbuf[2048];       // 8 KB
    int tid = threadIdx.x;
    int c = tid & 63;
    int g = tid >> 6;
    int n0 = blockIdx.x * 64;

#define STAGE(ARR, K0)                                                          \
    for (int j = tid; j < 512; j += 256) {                                      \
        int n = j >> 3, q = j & 7; int gi = n0 + n;                             \
        float4 v = (gi < N) ? *(const float4*)((ARR) + (size_t)gi * 32 + q * 4) \
                            : make_float4(0.f, 0.f, 0.f, 0.f);                  \
        *(float4*)&A[n * 160 + (K0) + q * 4] = v;                               \
    }
    STAGE(x, 0) STAGE(txo1, 32) STAGE(txi1, 64) STAGE(txo2, 96) STAGE(txi2, 128)
#undef STAGE

    float az0=0,az1=0,az2=0,az3=0,az4=0,az5=0,az6=0,az7=0,
          az8=0,az9=0,az10=0,az11=0,az12=0,az13=0,az14=0,az15=0;
    float ah0=0,ah1=0,ah2=0,ah3=0,ah4=0,ah5=0,ah6=0,ah7=0,
          ah8=0,ah9=0,ah10=0,ah11=0,ah12=0,ah13=0,ah14=0,ah15=0;

    for (int ck = 0; ck < 10; ++ck) {
        __syncthreads();
        for (int j = tid; j < 1024; j += 256) {
            int kl = j >> 6, cc = j & 63;
            int k = ck * 16 + kl;
            int blk = k >> 5, r = k & 31;
            float vz, vh;
            if (blk == 0) {
                vz = Wz[r * 64 + cc] + Wz[(288 + r) * 64 + cc];
                vh = Wh[r * 64 + cc] + Wh[(288 + r) * 64 + cc];
            } else {
                int kk = (blk + 1) >> 1, dd = (blk + 1) & 1;
                int off = ((dd * 3 + kk) * 96 + r) * 64 + cc;
                vz = Wz[off]; vh = Wh[off];
            }
            wbuf[j] = vz; wbuf[1024 + j] = vh;
        }
        __syncthreads();
#pragma unroll
        for (int k4 = 0; k4 < 4; ++k4) {
            float z0 = wbuf[(k4 * 4 + 0) * 64 + c];
            float z1 = wbuf[(k4 * 4 + 1) * 64 + c];
            float z2 = wbuf[(k4 * 4 + 2) * 64 + c];
            float z3 = wbuf[(k4 * 4 + 3) * 64 + c];
            float h0 = wbuf[1024 + (k4 * 4 + 0) * 64 + c];
            float h1 = wbuf[1024 + (k4 * 4 + 1) * 64 + c];
            float h2 = wbuf[1024 + (k4 * 4 + 2) * 64 + c];
            float h3 = wbuf[1024 + (k4 * 4 + 3) * 64 + c];
            const float* Ab = &A[g * 16 * 160 + ck * 16 + k4 * 4];
#define ROW(nn, AZ, AH) {                                                   \
            float4 a = *(const float4*)(Ab + (nn) * 160);                   \
            AZ += a.x * z0 + a.y * z1 + a.z * z2 + a.w * z3;                \
            AH += a.x * h0 + a.y * h1 + a.z * h2 + a.w * h3; }
            ROW(0, az0, ah0)   ROW(1, az1, ah1)   ROW(2, az2, ah2)   ROW(3, az3, ah3)
            ROW(4, az4, ah4)   ROW(5, az5, ah5)   ROW(6, az6, ah6)   ROW(7, az7, ah7)
            ROW(8, az8, ah8)   ROW(9, az9, ah9)   ROW(10, az10, ah10) ROW(11, az11, ah11)
            ROW(12, az12, ah12) ROW(13, az13, ah13) ROW(14, az14, ah14) ROW(15, az15, ah15)
#undef ROW
        }
    }

    float bzc = bz[c], bhc = bh[c];
#define EPI(AZ, AH) { float zz = 1.f / (1.f + expf(-((AZ) + bzc)));         \
                      AH = (1.f - zz) * tanhf((AH) + bhc); }
    EPI(az0, ah0) EPI(az1, ah1) EPI(az2, ah2) EPI(az3, ah3)
    EPI(az4, ah4) EPI(az5, ah5) EPI(az6, ah6) EPI(az7, ah7)
    EPI(az8, ah8) EPI(az9, ah9) EPI(az10, ah10) EPI(az11, ah11)
    EPI(az12, ah12) EPI(az13, ah13) EPI(az14, ah14) EPI(az15, ah15)
#undef EPI

    __syncthreads();
    {
        float* Ht = &A[g * 16 * 64 + c];
        Ht[0 * 64] = ah0;  Ht[1 * 64] = ah1;  Ht[2 * 64] = ah2;  Ht[3 * 64] = ah3;
        Ht[4 * 64] = ah4;  Ht[5 * 64] = ah5;  Ht[6 * 64] = ah6;  Ht[7 * 64] = ah7;
        Ht[8 * 64] = ah8;  Ht[9 * 64] = ah9;  Ht[10 * 64] = ah10; Ht[11 * 64] = ah11;
        Ht[12 * 64] = ah12; Ht[13 * 64] = ah13; Ht[14 * 64] = ah14; Ht[15 * 64] = ah15;
    }

    float b0=0,b1=0,b2=0,b3=0,b4=0,b5=0,b6=0,b7=0,
          b8=0,b9=0,b10=0,b11=0,b12=0,b13=0,b14=0,b15=0;
    for (int ck = 0; ck < 2; ++ck) {
        __syncthreads();
        for (int j = tid; j < 2048; j += 256)
            wbuf[j] = gcn_w[ck * 2048 + j];
        __syncthreads();
#pragma unroll
        for (int k4 = 0; k4 < 8; ++k4) {
            float g0 = wbuf[(k4 * 4 + 0) * 64 + c];
            float g1 = wbuf[(k4 * 4 + 1) * 64 + c];
            float g2 = wbuf[(k4 * 4 + 2) * 64 + c];
            float g3 = wbuf[(k4 * 4 + 3) * 64 + c];
            const float* Hb = &A[g * 16 * 64 + ck * 32 + k4 * 4];
#define ROW2(nn, B) { float4 a = *(const float4*)(Hb + (nn) * 64);          \
                      B += a.x * g0 + a.y * g1 + a.z * g2 + a.w * g3; }
            ROW2(0, b0)  ROW2(1, b1)  ROW2(2, b2)  ROW2(3, b3)
            ROW2(4, b4)  ROW2(5, b5)  ROW2(6, b6)  ROW2(7, b7)
            ROW2(8, b8)  ROW2(9, b9)  ROW2(10, b10) ROW2(11, b11)
            ROW2(12, b12) ROW2(13, b13) ROW2(14, b14) ROW2(15, b15)
#undef ROW2
        }
    }
    int nb = n0 + g * 16;
#define ST(nn, B) if (nb + (nn) < N) xws[(size_t)(nb + (nn)) * 64 + c] = dis[nb + (nn)] * (B);
    ST(0, b0)  ST(1, b1)  ST(2, b2)  ST(3, b3)
    ST(4, b4)  ST(5, b5)  ST(6, b6)  ST(7, b7)
    ST(8, b8)  ST(9, b9)  ST(10, b10) ST(11, b11)
    ST(12, b12) ST(13, b13) ST(14, b14) ST(15, b15)
#undef ST
}

// GCN gather + bias + ReLU + BN stats. y[d] = relu(dis[d]*(xws[d]+sum xws[src])+b)
__global__ __launch_bounds__(256) void k_gcn_fused(
    const int2* __restrict__ ent_col,
    const int* __restrict__ off_col, const int* __restrict__ cnt_col,
    const float* __restrict__ dis, const float* __restrict__ xws,
    const float* __restrict__ gcn_b,
    float* __restrict__ y, float* __restrict__ stats, int N) {
    __shared__ float red[2][256];
    int lane = threadIdx.x & 63;
    int wid  = threadIdx.x >> 6;
    int wave = (blockIdx.x * blockDim.x + threadIdx.x) >> 6;
    int nw = (gridDim.x * blockDim.x) >> 6;
    float bl = gcn_b[lane];
    float s = 0.f, s2 = 0.f;
    for (int d = wave; d < N; d += nw) {
        float sum = xws[(size_t)d * 64 + lane];
        int base = off_col[d], cnt = cnt_col[d];
        int j = 0;
        for (; j + 3 < cnt; j += 4) {
            int2 e0 = ent_col[base + j],     e1 = ent_col[base + j + 1];
            int2 e2 = ent_col[base + j + 2], e3 = ent_col[base + j + 3];
            float v0 = xws[(size_t)e0.x * 64 + lane];
            float v1 = xws[(size_t)e1.x * 64 + lane];
            float v2 = xws[(size_t)e2.x * 64 + lane];
            float v3 = xws[(size_t)e3.x * 64 + lane];
            sum += v0 + v1 + v2 + v3;
        }
        for (; j < cnt; ++j) {
            int2 e0 = ent_col[base + j];
            sum += xws[(size_t)e0.x * 64 + lane];
        }
        float v = dis[d] * sum + bl;
        v = v > 0.f ? v : 0.f;
        y[(size_t)d * 64 + lane] = v;
        s += v; s2 += v * v;
    }
    red[0][threadIdx.x] = s;
    red[1][threadIdx.x] = s2;
    __syncthreads();
    if (wid == 0) {
        float ts  = red[0][lane] + red[0][64 + lane] + red[0][128 + lane] + red[0][192 + lane];
        float ts2 = red[1][lane] + red[1][64 + lane] + red[1][128 + lane] + red[1][192 + lane];
        atomicAdd(&stats[lane], ts);
        atomicAdd(&stats[64 + lane], ts2);
    }
}

// out[i] = sum_f ((y[i,f]-mean)*istd*gamma + beta) * lw[f] + lb   (wave per node)
__global__ void k_final(const float* __restrict__ y, const float* __restrict__ stats,
                        const float* __restrict__ gma, const float* __restrict__ bta,
                        const float* __restrict__ lw, const float* __restrict__ lb,
                        float* __restrict__ out, int N) {
    int lane = threadIdx.x & 63;
    int wave = (blockIdx.x * blockDim.x + threadIdx.x) >> 6;
    if (wave >= N) return;
    float invN = 1.0f / (float)N;
    float mean = stats[lane] * invN;
    float var  = stats[64 + lane] * invN - mean * mean;   // biased var
    float istd = rsqrtf(var + BN_EPS);
    float v = y[(size_t)wave * 64 + lane];
    float t = (v - mean) * istd * gma[lane] + bta[lane];
    float p = t * lw[lane];
    for (int off = 32; off > 0; off >>= 1)
        p += __shfl_down(p, off, 64);
    if (lane == 0) out[wave] = p + lb[0];
}

extern "C" void kernel_launch(void* const* d_in, const int* in_sizes, int n_in,
                              void* d_out, int out_size, void* d_ws, size_t ws_size,
                              hipStream_t stream) {
    const float* x     = (const float*)d_in[0];
    const int*   ei    = (const int*)d_in[1];
    const float* ew    = (const float*)d_in[2];
    const float* Wz    = (const float*)d_in[3];
    const float* bz    = (const float*)d_in[4];
    // d_in[5] = Wr, d_in[6] = br : provably unused (H0 == 0)
    const float* Wh    = (const float*)d_in[7];
    const float* bhv   = (const float*)d_in[8];
    const float* gcn_w = (const float*)d_in[9];
    const float* gcn_b = (const float*)d_in[10];
    const float* gma   = (const float*)d_in[11];
    const float* bta   = (const float*)d_in[12];
    const float* lw    = (const float*)d_in[13];
    const float* lb    = (const float*)d_in[14];
    float* out = (float*)d_out;

    const int N = in_sizes[0] / 32;
    const int E = in_sizes[2];
    const int* row = ei;
    const int* col = ei + E;
    const int NB = (N + 255) / 256;       // 196 <= 256

    // workspace layout (4-byte words)
    float* ws      = (float*)d_ws;
    int*   cnt_col = (int*)ws;                        // N
    int*   cnt_row = (int*)(ws + (size_t)N);          // N
    int*   cur_col = (int*)(ws + 2 * (size_t)N);      // N
    int*   cur_row = (int*)(ws + 3 * (size_t)N);      // N
    float* stats   = ws + 4 * (size_t)N;              // 128
    int*   bsum    = (int*)(ws + 4 * (size_t)N + 128);// 512  <- end of zero region
    size_t Z0      = 4 * (size_t)N + 640;
    int*   off_col = (int*)(ws + Z0);                 // N
    int*   off_row = (int*)(ws + Z0 + N);             // N
    float* dis     = ws + Z0 + 2 * (size_t)N;         // N
    float* do_inv  = ws + Z0 + 3 * (size_t)N;         // N
    float* di_inv  = ws + Z0 + 4 * (size_t)N;         // N
    float* xo0     = ws + Z0 + 5 * (size_t)N;         // 32N (later overlaid by txo2)
    float* xi0     = xo0 + 32 * (size_t)N;            // 32N (later overlaid by txi2)
    float* txo1    = xi0 + 32 * (size_t)N;            // 32N
    float* txi1    = txo1 + 32 * (size_t)N;           // 32N
    int2*  ent_col = (int2*)(txi1 + 32 * (size_t)N);  // E int2 (2E words)
    int2*  ent_row = (int2*)((float*)ent_col + 2 * (size_t)E); // E int2
    float* xws     = (float*)ent_row;                 // 64N (overlay: ent_row dead after hop2)
    float* txo2    = xo0;                             // overlay (xo0 dead after hop1)
    float* txi2    = xi0;                             // overlay
    float* ybuf    = txo1;                            // 64N (txo1+txi1 dead after k_zh)

    size_t zero_bytes = (4 * (size_t)N + 640) * sizeof(float);
    hipMemsetAsync(d_ws, 0, zero_bytes, stream);

    int be = (E + 255) / 256;
    k_cnt  <<<be, 256, 0, stream>>>(row, col, cnt_col, cnt_row, E);
    k_scan1<<<2 * NB, 256, 0, stream>>>(cnt_col, cnt_row, bsum, NB, N);
    k_scan2<<<2, 256, 0, stream>>>(bsum);
    k_scan3<<<2 * NB, 256, 0, stream>>>(cnt_col, cnt_row, bsum, off_col, off_row, NB, N);
    k_fill <<<be, 256, 0, stream>>>(row, col, ew, off_col, off_row,
                                    cur_col, cur_row, ent_col, ent_row, E);
    k_degs <<<NB, 256, 0, stream>>>(ent_col, ent_row, off_col, cnt_col,
                                    off_row, cnt_row, do_inv, di_inv, dis, N);
    k_pre  <<<(N * 32 + 255) / 256, 256, 0, stream>>>(x, do_inv, di_inv, xo0, xi0, N);

    int bhop = (2 * N * 32 + 255) / 256;
    k_hop1<<<bhop, 256, 0, stream>>>(ent_col, ent_row, off_col, off_row,
                                     cnt_col, cnt_row, xo0, xi0, txo1, txi1, N);
    k_hop2<<<bhop, 256, 0, stream>>>(ent_col, ent_row, off_col, off_row,
                                     cnt_col, cnt_row, txo1, txi1,
                                     do_inv, di_inv, txo2, txi2, N);

    k_zh<<<(N + 63) / 64, 256, 0, stream>>>(x, txo1, txi1, txo2, txi2,
                                            Wz, bz, Wh, bhv, gcn_w, dis, xws, N);

    k_gcn_fused<<<1600, 256, 0, stream>>>(ent_col, off_col, cnt_col, dis, xws,
                                          gcn_b, ybuf, stats, N);
    k_final<<<(N + 3) / 4, 256, 0, stream>>>(ybuf, stats, gma, bta, lw, lb, out, N);
}